// Round 8
// baseline (7240.486 us; speedup 1.0000x reference)
//
#include <hip/hip_runtime.h>

// DGCNN forward, fp32 throughout.
// R8: kNN selection rebuilt as lane-distributed sorted top-32 lists held in
// wave registers (2 slots/lane per row within each 16-lane group; insert =
// shfl_up shift, 6 shfl + ~12 VALU; thr = shfl of slot 19). No LDS lists, no
// atomics, no seed phase, no retry loops. GEMM upgraded to 128x128 tile with
// 8x8 micro (w5_pool-proven core). NSPL=4 splits -> 1024 blocks.

#define NPTS   4096
#define NB     8
#define BNR    32768      // NB*NPTS
#define KNN    20
#define EPSBN  1e-5f
#define NSPL   4          // column splits per row-block

__device__ __forceinline__ float lrelu(float x){ return x > 0.f ? x : 0.2f*x; }

__device__ __forceinline__ void topk_insert(float (&bv)[KNN], int (&bi)[KNN], float d, int mi){
#pragma unroll
  for (int j = 0; j < KNN; ++j){
    bool take = d > bv[j];
    float nv = take ? d : bv[j];
    int   ni = take ? mi : bi[j];
    float od = take ? bv[j] : d;
    int   oi = take ? bi[j] : mi;
    bv[j] = nv; bi[j] = ni; d = od; mi = oi;
  }
}

// x (8,6,4096) -> xt (8,4096,8), channels 6,7 zero-padded
__global__ __launch_bounds__(256) void k_transpose_pad(const float* __restrict__ x,
                                                       float* __restrict__ xt){
  int id = blockIdx.x*256 + threadIdx.x;          // 0..32767
  int b = id >> 12, n = id & (NPTS-1);
  const float* xb = x + (size_t)b*6*NPTS + n;
  float* o = xt + (size_t)id*8;
#pragma unroll
  for (int c = 0; c < 6; ++c) o[c] = xb[(size_t)c*NPTS];
  o[6] = 0.f; o[7] = 0.f;
}

// squared norm per row (c4 float4 groups, row stride xstride floats)
__global__ __launch_bounds__(256) void k_sqnorm(const float* __restrict__ X, int xstride, int c4,
                                                float* __restrict__ sq){
  int id = blockIdx.x*256 + threadIdx.x;
  const float4* r = (const float4*)(X + (size_t)id*xstride);
  float s = 0.f;
  for (int c = 0; c < c4; ++c){ float4 v = r[c]; s += v.x*v.x + v.y*v.y + v.z*v.z + v.w*v.w; }
  sq[id] = s;
}

// Fused kNN: block = 128 rows x (NPTS/NSPL) cols of one batch, 8x8 micro GEMM.
// Per 16-lane group: 8 rows; each row's top-32 (only 0..19 used) distributed
// across lanes: slot tx in s0, slot 16+tx in s1. Sorted desc, stable ties.
template<int K>
__global__ __launch_bounds__(256,3) void k_knn_fused(const float* __restrict__ X, int xstride,
                                                     const float* __restrict__ sqv,
                                                     float* __restrict__ cand_v,
                                                     int* __restrict__ cand_i){
  constexpr int BK   = (K < 32) ? K : 32;
  constexpr int COLS = NPTS / NSPL;
  __shared__ float As[BK][132];
  __shared__ float Bs[BK][132];
  __shared__ float sqs[128];

  const int b  = blockIdx.z;
  const int i0 = blockIdx.x * 128;
  const int sp = blockIdx.y;
  const int c0 = sp * COLS;
  const int tid = threadIdx.x, tx = tid & 15, ty = tid >> 4;
  const int lane = tid & 63, gb = lane & 48;
  const float* Xb  = X + (size_t)b * NPTS * xstride;
  const float* sqb = sqv + b * NPTS;

  float s0v[8], s1v[8]; int s0c[8], s1c[8];
#pragma unroll
  for (int r = 0; r < 8; ++r){ s0v[r] = -3e38f; s1v[r] = -3e38f; s0c[r] = 0; s1c[r] = 0; }

  float sqi[8];
#pragma unroll
  for (int r = 0; r < 8; ++r) sqi[r] = sqb[i0 + ty*8 + r];

  for (int j0 = c0; j0 < c0 + COLS; j0 += 128){
    float acc[8][8] = {};
    float sq8[8];
    for (int k0 = 0; k0 < K; k0 += BK){
#pragma unroll
      for (int i = 0; i < BK/2; ++i){
        int li = tid + 256*i;
        int row = li / BK, kk = li % BK;      // BK is pow2
        As[kk][row] = Xb[(size_t)(i0+row)*xstride + k0+kk];
        Bs[kk][row] = Xb[(size_t)(j0+row)*xstride + k0+kk];
      }
      if (k0 == 0 && tid < 128) sqs[tid] = sqb[j0 + tid];
      __syncthreads();
      if (k0 == 0){
#pragma unroll
        for (int c = 0; c < 4; ++c){ sq8[c] = sqs[tx*4 + c]; sq8[c+4] = sqs[64 + tx*4 + c]; }
      }
#pragma unroll
      for (int kk = 0; kk < BK; ++kk){
        float a[8], bb_[8];
        *(float4*)&a[0]   = *(const float4*)&As[kk][ty*8];
        *(float4*)&a[4]   = *(const float4*)&As[kk][ty*8+4];
        *(float4*)&bb_[0] = *(const float4*)&Bs[kk][tx*4];
        *(float4*)&bb_[4] = *(const float4*)&Bs[kk][64 + tx*4];
#pragma unroll
        for (int r = 0; r < 8; ++r)
#pragma unroll
          for (int c = 0; c < 8; ++c)
            acc[r][c] = fmaf(a[r], bb_[c], acc[r][c]);
      }
      __syncthreads();
    }
    // ---- selection: register-distributed sorted insert ----
#pragma unroll
    for (int r = 0; r < 8; ++r){
      float va[8];
#pragma unroll
      for (int j = 0; j < 8; ++j) va[j] = 2.f*acc[r][j] - sqi[r] - sq8[j];
      float thr = __shfl(s1v[r], gb + 3);           // slot 19
      bool any = false;
#pragma unroll
      for (int j = 0; j < 8; ++j) any |= (va[j] > thr);
      if (((__ballot(any) >> gb) & 0xFFFFull) == 0ull) continue;
#pragma unroll
      for (int j = 0; j < 8; ++j){
        while (true){
          unsigned long long bal = __ballot(va[j] > thr);
          unsigned m = (unsigned)((bal >> gb) & 0xFFFFull);
          if (!m) break;
          int l = __ffs(m) - 1;
          float bv = __shfl(va[j], gb + l);
          int   bc = j0 + ((j < 4) ? (l*4 + j) : (64 + l*4 + j - 4));
          // distributed insert into sorted-32 (desc, stable)
          float up0v = __shfl_up(s0v[r], 1); int up0c = __shfl_up(s0c[r], 1);
          float c15v = __shfl(s0v[r], gb + 15); int c15c = __shfl(s0c[r], gb + 15);
          float up1v = __shfl_up(s1v[r], 1); int up1c = __shfl_up(s1c[r], 1);
          if (tx == 0){ up1v = c15v; up1c = c15c; }
          bool i0_ = bv > s0v[r];
          bool p0_ = (tx > 0) && (bv > up0v);
          if (i0_){ s0v[r] = p0_ ? up0v : bv; s0c[r] = p0_ ? up0c : bc; }
          bool i1_ = bv > s1v[r];
          bool p1_ = bv > up1v;
          if (i1_){ s1v[r] = p1_ ? up1v : bv; s1c[r] = p1_ ? up1c : bc; }
          if (tx == l) va[j] = -3e38f;
          thr = __shfl(s1v[r], gb + 3);
        }
      }
    }
  }
#pragma unroll
  for (int r = 0; r < 8; ++r){
    int gn = b*NPTS + i0 + ty*8 + r;
    size_t base = ((size_t)gn*NSPL + sp)*KNN;
    cand_v[base + tx] = s0v[r];
    cand_i[base + tx] = s0c[r];
    if (tx < 4){ cand_v[base + 16 + tx] = s1v[r]; cand_i[base + 16 + tx] = s1c[r]; }
  }
}

// merge NSPL per-split sorted top-20 lists -> final top-20 per row.
// splits ascending (ascending col ranges) + strict > insert: stable tie-break.
__global__ __launch_bounds__(256) void k_knn_merge(const float* __restrict__ cand_v,
                                                   const int* __restrict__ cand_i,
                                                   int* __restrict__ idx){
  int gn = blockIdx.x*256 + threadIdx.x;
  float bv[KNN]; int bi[KNN];
#pragma unroll
  for (int j = 0; j < KNN; ++j){ bv[j] = -3e38f; bi[j] = -1; }
  for (int s = 0; s < NSPL; ++s){
#pragma unroll 1
    for (int t = 0; t < KNN; ++t){
      float d  = cand_v[((size_t)gn*NSPL + s)*KNN + t];
      int   mi = cand_i[((size_t)gn*NSPL + s)*KNN + t];
      if (d > bv[KNN-1]) topk_insert(bv, bi, d, mi);
    }
  }
#pragma unroll
  for (int j = 0; j < KNN; ++j) idx[(size_t)gn*KNN + j] = bi[j];
}

// PQ(M x 2*Och) = X(M x Kdim) @ [Wa; Wb]^T where Wa=W[:, :Kdim], Wb=W[:, Kdim:2Kdim].
// BM=128, BO=64, BK=16, 8x4 micro.
__global__ __launch_bounds__(256) void k_gemm_pq(const float* __restrict__ X, int xstride, int Kdim,
                                                 const float* __restrict__ W, int wstride, int Och,
                                                 float* __restrict__ PQ){
  __shared__ float Xs[16][132];
  __shared__ float Ws[16][68];
  const int m0 = blockIdx.x*128, o0 = blockIdx.y*64;
  const int tid = threadIdx.x, tx = tid & 15, ty = tid >> 4;
  const int O2 = 2*Och;
  float acc[8][4] = {};
  for (int k0 = 0; k0 < Kdim; k0 += 16){
#pragma unroll
    for (int i = 0; i < 8; ++i){
      int li = tid + 256*i;
      int row = li >> 4, kk = li & 15;
      bool ok = (k0 + kk) < Kdim;
      Xs[kk][row] = ok ? X[(size_t)(m0+row)*xstride + k0+kk] : 0.f;
    }
#pragma unroll
    for (int i = 0; i < 4; ++i){
      int li = tid + 256*i;
      int row = li >> 4, kk = li & 15;
      int orow = o0 + row;
      const float* wr = (orow < Och) ? (W + (size_t)orow*wstride)
                                     : (W + (size_t)(orow-Och)*wstride + Kdim);
      bool ok = (k0 + kk) < Kdim;
      Ws[kk][row] = ok ? wr[k0+kk] : 0.f;
    }
    __syncthreads();
#pragma unroll
    for (int kk = 0; kk < 16; ++kk){
      float xa[8], wb[4];
      *(float4*)&xa[0] = *(const float4*)&Xs[kk][ty*8];
      *(float4*)&xa[4] = *(const float4*)&Xs[kk][ty*8+4];
      *(float4*)wb     = *(const float4*)&Ws[kk][tx*4];
#pragma unroll
      for (int i = 0; i < 8; ++i)
#pragma unroll
        for (int j = 0; j < 4; ++j)
          acc[i][j] = fmaf(xa[i], wb[j], acc[i][j]);
    }
    __syncthreads();
  }
#pragma unroll
  for (int i = 0; i < 8; ++i){
    float4 v = make_float4(acc[i][0], acc[i][1], acc[i][2], acc[i][3]);
    *(float4*)&PQ[(size_t)(m0+ty*8+i)*O2 + o0 + tx*4] = v;
  }
}

// out[n,o] = lrelu(scale*(red_k P[mk,o] - P[n,o] + Q[n,o]) + beta); red=max if scale>=0 else min
// P(m,o) = PQ[m*2O + o]; Q(n,o) = PQ[n*2O + O + o]
__global__ __launch_bounds__(256) void k_gather_conv(const float* __restrict__ PQ,
                                                     const int* __restrict__ idx,
                                                     const float* __restrict__ g,
                                                     const float* __restrict__ bb,
                                                     const float* __restrict__ rm,
                                                     const float* __restrict__ rv,
                                                     float* __restrict__ Out, int oshift, int choff){
  const int O = 1 << oshift;
  int id = blockIdx.x*256 + threadIdx.x;
  int gn = id >> oshift;
  int o  = id & (O-1);
  int bbase = (gn >> 12) * NPTS;
  const int* ip = idx + (size_t)gn*KNN;
  float vmax = -3e38f, vmin = 3e38f;
#pragma unroll
  for (int k = 0; k < KNN; ++k){
    int m = ip[k];
    float v = PQ[((size_t)(bbase + m) << (oshift+1)) + o];
    vmax = fmaxf(vmax, v);
    vmin = fminf(vmin, v);
  }
  float scale = g[o] * rsqrtf(rv[o] + EPSBN);
  float beta  = bb[o] - rm[o]*scale;
  float R = (scale >= 0.f) ? vmax : vmin;
  size_t self = (size_t)gn << (oshift+1);
  float h = R - PQ[self + o] + PQ[self + O + o];
  Out[(size_t)gn*512 + choff + o] = lrelu(fmaf(scale, h, beta));
}

// h = lrelu(bn(xc @ W5^T)) tile (128x128, 8x8 micro, split col groups),
// fused partial max/sum over rows.
__global__ __launch_bounds__(256) void k_gemm_w5_pool(const float* __restrict__ X,
                                                      const float* __restrict__ W,
                                                      const float* __restrict__ g,
                                                      const float* __restrict__ bb,
                                                      const float* __restrict__ rm,
                                                      const float* __restrict__ rv,
                                                      float* __restrict__ pmax,
                                                      float* __restrict__ psum){
  __shared__ float Xs[16][132];
  __shared__ float Ws[16][132];
  __shared__ float red[2][16][128];
  const int m0 = blockIdx.x*128, o0 = blockIdx.y*128;
  const int tid = threadIdx.x, tx = tid & 15, ty = tid >> 4;
  float acc[8][8] = {};
  for (int k0 = 0; k0 < 512; k0 += 16){
#pragma unroll
    for (int i = 0; i < 8; ++i){
      int li = tid + 256*i;
      int row = li >> 4, kk = li & 15;
      Xs[kk][row] = X[(size_t)(m0+row)*512 + k0+kk];
      Ws[kk][row] = W[(size_t)(o0+row)*512 + k0+kk];
    }
    __syncthreads();
#pragma unroll
    for (int kk = 0; kk < 16; ++kk){
      float xa[8], wb[8];
      *(float4*)&xa[0] = *(const float4*)&Xs[kk][ty*8];
      *(float4*)&xa[4] = *(const float4*)&Xs[kk][ty*8+4];
      *(float4*)&wb[0] = *(const float4*)&Ws[kk][tx*4];
      *(float4*)&wb[4] = *(const float4*)&Ws[kk][64 + tx*4];
#pragma unroll
      for (int i = 0; i < 8; ++i)
#pragma unroll
        for (int j = 0; j < 8; ++j)
          acc[i][j] = fmaf(xa[i], wb[j], acc[i][j]);
    }
    __syncthreads();
  }
#pragma unroll
  for (int j = 0; j < 8; ++j){
    int ocol = (j < 4) ? (tx*4 + j) : (64 + tx*4 + j - 4);
    int o = o0 + ocol;
    float scale = g[o] * rsqrtf(rv[o] + EPSBN);
    float beta  = bb[o] - rm[o]*scale;
    float mx = -3e38f, sm = 0.f;
#pragma unroll
    for (int i = 0; i < 8; ++i){
      float h = lrelu(fmaf(scale, acc[i][j], beta));
      mx = fmaxf(mx, h);
      sm += h;
    }
    red[0][ty][ocol] = mx;
    red[1][ty][ocol] = sm;
  }
  __syncthreads();
  if (tid < 128){
    float mx = -3e38f, sm = 0.f;
#pragma unroll
    for (int t = 0; t < 16; ++t){
      mx = fmaxf(mx, red[0][t][tid]);
      sm += red[1][t][tid];
    }
    pmax[(size_t)blockIdx.x*1024 + o0 + tid] = mx;
    psum[(size_t)blockIdx.x*1024 + o0 + tid] = sm;
  }
}

__global__ __launch_bounds__(256) void k_pool_reduce(const float* __restrict__ pmax,
                                                     const float* __restrict__ psum,
                                                     float* __restrict__ pooled){
  int id = blockIdx.x*256 + threadIdx.x;   // 8192
  int b = id >> 10, o = id & 1023;
  float mx = -3e38f, sm = 0.f;
  for (int t = 0; t < 32; ++t){
    mx = fmaxf(mx, pmax[(size_t)(b*32+t)*1024 + o]);
    sm += psum[(size_t)(b*32+t)*1024 + o];
  }
  pooled[(size_t)b*2048 + o] = mx;
  pooled[(size_t)b*2048 + 1024 + o] = sm * (1.f/NPTS);
}

__global__ __launch_bounds__(256) void k_fc1(const float* __restrict__ pooled,
                                             const float* __restrict__ W,
                                             const float* __restrict__ g,
                                             const float* __restrict__ bb,
                                             const float* __restrict__ rm,
                                             const float* __restrict__ rv,
                                             float* __restrict__ out){
  __shared__ float4 xs[512];
  int b = blockIdx.x >> 1;
  int o = ((blockIdx.x & 1) << 8) + threadIdx.x;
  const float4* pr = (const float4*)(pooled + (size_t)b*2048);
  for (int l = threadIdx.x; l < 512; l += 256) xs[l] = pr[l];
  __syncthreads();
  const float4* wr = (const float4*)(W + (size_t)o*2048);
  float s0=0.f, s1=0.f, s2=0.f, s3=0.f;
#pragma unroll 4
  for (int c = 0; c < 512; ++c){
    float4 w = wr[c], v = xs[c];
    s0 = fmaf(v.x, w.x, s0); s1 = fmaf(v.y, w.y, s1);
    s2 = fmaf(v.z, w.z, s2); s3 = fmaf(v.w, w.w, s3);
  }
  float h = (s0+s1)+(s2+s3);
  float scale = g[o] * rsqrtf(rv[o] + EPSBN);
  float beta  = bb[o] - rm[o]*scale;
  out[(size_t)b*512 + o] = lrelu(fmaf(scale, h, beta));
}

__global__ __launch_bounds__(256) void k_fc2(const float* __restrict__ in,
                                             const float* __restrict__ W,
                                             const float* __restrict__ bias,
                                             const float* __restrict__ g,
                                             const float* __restrict__ bb,
                                             const float* __restrict__ rm,
                                             const float* __restrict__ rv,
                                             float* __restrict__ out){
  __shared__ float4 xs[128];
  int b = blockIdx.x;
  int o = threadIdx.x;
  const float4* pr = (const float4*)(in + (size_t)b*512);
  if (threadIdx.x < 128) xs[threadIdx.x] = pr[threadIdx.x];
  __syncthreads();
  const float4* wr = (const float4*)(W + (size_t)o*512);
  float s0=0.f, s1=0.f, s2=0.f, s3=0.f;
#pragma unroll 4
  for (int c = 0; c < 128; ++c){
    float4 w = wr[c], v = xs[c];
    s0 = fmaf(v.x, w.x, s0); s1 = fmaf(v.y, w.y, s1);
    s2 = fmaf(v.z, w.z, s2); s3 = fmaf(v.w, w.w, s3);
  }
  float h = (s0+s1)+(s2+s3) + bias[o];
  float scale = g[o] * rsqrtf(rv[o] + EPSBN);
  float beta  = bb[o] - rm[o]*scale;
  out[(size_t)b*256 + o] = lrelu(fmaf(scale, h, beta));
}

__global__ __launch_bounds__(64) void k_fc3(const float* __restrict__ in,
                                            const float* __restrict__ W,
                                            const float* __restrict__ bias,
                                            float* __restrict__ out){
  int t = threadIdx.x;
  if (t >= 16) return;
  int b = t >> 1, o = t & 1;
  const float* xr = in + (size_t)b*256;
  const float* wr = W + (size_t)o*256;
  float s = 0.f;
  for (int c = 0; c < 256; ++c) s = fmaf(xr[c], wr[c], s);
  out[b*2 + o] = s + bias[o];
}

extern "C" void kernel_launch(void* const* d_in, const int* in_sizes, int n_in,
                              void* d_out, int out_size, void* d_ws, size_t ws_size,
                              hipStream_t stream){
  (void)in_sizes; (void)n_in; (void)out_size;
  const float* x   = (const float*)d_in[0];
  const float* W1  = (const float*)d_in[1];
  const float* g1  = (const float*)d_in[2];
  const float* b1  = (const float*)d_in[3];
  const float* m1  = (const float*)d_in[4];
  const float* v1  = (const float*)d_in[5];
  const float* W2  = (const float*)d_in[6];
  const float* g2  = (const float*)d_in[7];
  const float* b2  = (const float*)d_in[8];
  const float* m2  = (const float*)d_in[9];
  const float* v2  = (const float*)d_in[10];
  const float* W3  = (const float*)d_in[11];
  const float* g3  = (const float*)d_in[12];
  const float* b3  = (const float*)d_in[13];
  const float* m3  = (const float*)d_in[14];
  const float* v3  = (const float*)d_in[15];
  const float* W4  = (const float*)d_in[16];
  const float* g4  = (const float*)d_in[17];
  const float* b4  = (const float*)d_in[18];
  const float* m4  = (const float*)d_in[19];
  const float* v4  = (const float*)d_in[20];
  const float* W5  = (const float*)d_in[21];
  const float* g5  = (const float*)d_in[22];
  const float* b5  = (const float*)d_in[23];
  const float* m5  = (const float*)d_in[24];
  const float* v5  = (const float*)d_in[25];
  const float* L1  = (const float*)d_in[26];
  const float* gl1 = (const float*)d_in[27];
  const float* bl1 = (const float*)d_in[28];
  const float* ml1 = (const float*)d_in[29];
  const float* vl1 = (const float*)d_in[30];
  const float* L2  = (const float*)d_in[31];
  const float* L2b = (const float*)d_in[32];
  const float* gl2 = (const float*)d_in[33];
  const float* bl2 = (const float*)d_in[34];
  const float* ml2 = (const float*)d_in[35];
  const float* vl2 = (const float*)d_in[36];
  const float* L3  = (const float*)d_in[37];
  const float* L3b = (const float*)d_in[38];

  // workspace layout (float offsets)
  float* ws    = (float*)d_ws;
  float* xt    = ws;                      //   262144
  float* sq    = ws + 262144;             //    32768
  int*   idx   = (int*)(ws + 294912);     //   655360 ints
  float* candv = ws + 950272;             //  2621440 (BNR*NSPL*20)
  int*   candi = (int*)(ws + 3571712);    //  2621440 ints
  float* PQ    = ws + 6193152;            // 16777216 (max: 32768 x 512)
  float* xc    = ws + 22970368;           // 16777216  (8,4096,512) concat x1..x4
  float* pmax  = ws + 39747584;           //   262144
  float* psum  = ws + 40009728;           //   262144
  float* pool  = ws + 40271872;           //    16384
  float* oA    = ws + 40288256;           //     4096
  float* oB    = ws + 40292352;           //     2048
  if (ws_size < (size_t)40294400 * 4) return;  // ~161 MB scratch

  k_transpose_pad<<<128, 256, 0, stream>>>(x, xt);

  // ---- edge conv 1: in xt (C=6 padded to 8), out xc[:,:,0:64] ----
  k_sqnorm<<<128, 256, 0, stream>>>(xt, 8, 2, sq);
  k_knn_fused<8><<<dim3(32,NSPL,8), 256, 0, stream>>>(xt, 8, sq, candv, candi);
  k_knn_merge<<<128, 256, 0, stream>>>(candv, candi, idx);
  k_gemm_pq<<<dim3(256,2), 256, 0, stream>>>(xt, 8, 6, W1, 12, 64, PQ);
  k_gather_conv<<<8192, 256, 0, stream>>>(PQ, idx, g1, b1, m1, v1, xc, 6, 0);

  // ---- edge conv 2: in xc[:,:,0:64], out xc[:,:,64:128] ----
  k_sqnorm<<<128, 256, 0, stream>>>(xc, 512, 16, sq);
  k_knn_fused<64><<<dim3(32,NSPL,8), 256, 0, stream>>>(xc, 512, sq, candv, candi);
  k_knn_merge<<<128, 256, 0, stream>>>(candv, candi, idx);
  k_gemm_pq<<<dim3(256,2), 256, 0, stream>>>(xc, 512, 64, W2, 128, 64, PQ);
  k_gather_conv<<<8192, 256, 0, stream>>>(PQ, idx, g2, b2, m2, v2, xc, 6, 64);

  // ---- edge conv 3: in xc[:,:,64:128], out xc[:,:,128:256] ----
  k_sqnorm<<<128, 256, 0, stream>>>(xc + 64, 512, 16, sq);
  k_knn_fused<64><<<dim3(32,NSPL,8), 256, 0, stream>>>(xc + 64, 512, sq, candv, candi);
  k_knn_merge<<<128, 256, 0, stream>>>(candv, candi, idx);
  k_gemm_pq<<<dim3(256,4), 256, 0, stream>>>(xc + 64, 512, 64, W3, 128, 128, PQ);
  k_gather_conv<<<16384, 256, 0, stream>>>(PQ, idx, g3, b3, m3, v3, xc, 7, 128);

  // ---- edge conv 4: in xc[:,:,128:256], out xc[:,:,256:512] ----
  k_sqnorm<<<128, 256, 0, stream>>>(xc + 128, 512, 32, sq);
  k_knn_fused<128><<<dim3(32,NSPL,8), 256, 0, stream>>>(xc + 128, 512, sq, candv, candi);
  k_knn_merge<<<128, 256, 0, stream>>>(candv, candi, idx);
  k_gemm_pq<<<dim3(256,8), 256, 0, stream>>>(xc + 128, 512, 128, W4, 256, 256, PQ);
  k_gather_conv<<<32768, 256, 0, stream>>>(PQ, idx, g4, b4, m4, v4, xc, 8, 256);

  // ---- global feature: h = lrelu(bn(xc @ W5^T)), max+mean pool over N ----
  k_gemm_w5_pool<<<dim3(256,8), 256, 0, stream>>>(xc, W5, g5, b5, m5, v5, pmax, psum);
  k_pool_reduce<<<32, 256, 0, stream>>>(pmax, psum, pool);

  // ---- classifier head ----
  k_fc1<<<16, 256, 0, stream>>>(pool, L1, gl1, bl1, ml1, vl1, oA);
  k_fc2<<<8, 256, 0, stream>>>(oA, L2, L2b, gl2, bl2, ml2, vl2, oB);
  k_fc3<<<1, 64, 0, stream>>>(oB, L3, L3b, (float*)d_out);
}

// Round 9
// 4380.886 us; speedup vs baseline: 1.6527x; 1.6527x over previous
//
#include <hip/hip_runtime.h>

// DGCNN forward, fp32 throughout.
// R9: kNN = R4's GEMM skeleton (4x8 micro, BK<=32) + distance tile finalized
// into LDS (Dt aliases staging) + R2-PROVEN wave-cooperative ballot/shfl
// top-20 scan (each wave owns 16 rows; list distributed in lanes 0..19,
// 2 VGPR/row). No atomics, no candidate buffers, no flood case, no forced
// launch bounds (R8 spill lesson). NSPL=2 -> 1024 blocks, ~34KB LDS.

#define NPTS   4096
#define NB     8
#define BNR    32768      // NB*NPTS
#define KNN    20
#define EPSBN  1e-5f
#define NSPL   2          // column splits per row-block

__device__ __forceinline__ float lrelu(float x){ return x > 0.f ? x : 0.2f*x; }

__device__ __forceinline__ void topk_insert(float (&bv)[KNN], int (&bi)[KNN], float d, int mi){
#pragma unroll
  for (int j = 0; j < KNN; ++j){
    bool take = d > bv[j];
    float nv = take ? d : bv[j];
    int   ni = take ? mi : bi[j];
    float od = take ? bv[j] : d;
    int   oi = take ? bi[j] : mi;
    bv[j] = nv; bi[j] = ni; d = od; mi = oi;
  }
}

// x (8,6,4096) -> xt (8,4096,8), channels 6,7 zero-padded
__global__ __launch_bounds__(256) void k_transpose_pad(const float* __restrict__ x,
                                                       float* __restrict__ xt){
  int id = blockIdx.x*256 + threadIdx.x;          // 0..32767
  int b = id >> 12, n = id & (NPTS-1);
  const float* xb = x + (size_t)b*6*NPTS + n;
  float* o = xt + (size_t)id*8;
#pragma unroll
  for (int c = 0; c < 6; ++c) o[c] = xb[(size_t)c*NPTS];
  o[6] = 0.f; o[7] = 0.f;
}

// squared norm per row (c4 float4 groups, row stride xstride floats)
__global__ __launch_bounds__(256) void k_sqnorm(const float* __restrict__ X, int xstride, int c4,
                                                float* __restrict__ sq){
  int id = blockIdx.x*256 + threadIdx.x;
  const float4* r = (const float4*)(X + (size_t)id*xstride);
  float s = 0.f;
  for (int c = 0; c < c4; ++c){ float4 v = r[c]; s += v.x*v.x + v.y*v.y + v.z*v.z + v.w*v.w; }
  sq[id] = s;
}

// Fused kNN: block = 64 rows x (NPTS/NSPL) cols of one batch.
// Per chunk: GEMM (4x8 micro) -> finalize d into Dt -> per-wave ballot scan.
template<int K>
__global__ __launch_bounds__(256) void k_knn_fused(const float* __restrict__ X, int xstride,
                                                   const float* __restrict__ sqv,
                                                   float* __restrict__ cand_v,
                                                   int* __restrict__ cand_i){
  constexpr int BK    = (K < 32) ? K : 32;
  constexpr int COLS  = NPTS / NSPL;
  constexpr int STAGE = BK*68 + BK*132;
  constexpr int DTF   = 64*132;
  constexpr int SMEMF = (STAGE > DTF) ? STAGE : DTF;
  __shared__ __align__(16) float smem[SMEMF];
  __shared__ float sqs[128];
  float (*As)[68]  = (float(*)[68])smem;
  float (*Bs)[132] = (float(*)[132])(smem + BK*68);
  float (*Dt)[132] = (float(*)[132])smem;

  const int b  = blockIdx.z;
  const int i0 = blockIdx.x * 64;
  const int sp = blockIdx.y;
  const int c0 = sp * COLS;
  const int tid = threadIdx.x, tx = tid & 15, ty = tid >> 4;
  const int lane = tid & 63, wv = tid >> 6;
  const float* Xb  = X + (size_t)b * NPTS * xstride;
  const float* sqb = sqv + b * NPTS;

  // per-wave distributed top-20 lists: row wv*16+rr, slots in lanes 0..19
  float lv[16]; int li[16];
#pragma unroll
  for (int r = 0; r < 16; ++r){ lv[r] = -3e38f; li[r] = 0; }

  float sqi[4];
#pragma unroll
  for (int r = 0; r < 4; ++r) sqi[r] = sqb[i0 + ty*4 + r];

  for (int j0 = c0; j0 < c0 + COLS; j0 += 128){
    // ---- distance GEMM ----
    float acc[4][8] = {};
    for (int k0 = 0; k0 < K; k0 += BK){
      {
        int row = tid & 63, q = tid >> 6;
        const float* src = Xb + (size_t)(i0 + row)*xstride + k0;
#pragma unroll
        for (int k = q*(BK/4); k < (q+1)*(BK/4); ++k) As[k][row] = src[k];
      }
      {
        int col = tid & 127, h = tid >> 7;
        const float* src = Xb + (size_t)(j0 + col)*xstride + k0;
#pragma unroll
        for (int k = h*(BK/2); k < (h+1)*(BK/2); ++k) Bs[k][col] = src[k];
      }
      if (k0 == 0 && tid < 128) sqs[tid] = sqb[j0 + tid];
      __syncthreads();
#pragma unroll
      for (int kk = 0; kk < BK; ++kk){
        float a[4], bb_[8];
        *(float4*)a        = *(const float4*)&As[kk][ty*4];
        *(float4*)&bb_[0]  = *(const float4*)&Bs[kk][tx*4];
        *(float4*)&bb_[4]  = *(const float4*)&Bs[kk][64 + tx*4];
#pragma unroll
        for (int r = 0; r < 4; ++r)
#pragma unroll
          for (int c = 0; c < 8; ++c)
            acc[r][c] = fmaf(a[r], bb_[c], acc[r][c]);
      }
      __syncthreads();
    }
    // ---- finalize d = 2*acc - sq_i - sq_j into Dt (aliases staging) ----
    {
      float4 sjA = *(const float4*)&sqs[tx*4];
      float4 sjB = *(const float4*)&sqs[64 + tx*4];
#pragma unroll
      for (int r = 0; r < 4; ++r){
        int row = ty*4 + r;
        float4 vA = make_float4(2.f*acc[r][0]-sqi[r]-sjA.x, 2.f*acc[r][1]-sqi[r]-sjA.y,
                                2.f*acc[r][2]-sqi[r]-sjA.z, 2.f*acc[r][3]-sqi[r]-sjA.w);
        float4 vB = make_float4(2.f*acc[r][4]-sqi[r]-sjB.x, 2.f*acc[r][5]-sqi[r]-sjB.y,
                                2.f*acc[r][6]-sqi[r]-sjB.z, 2.f*acc[r][7]-sqi[r]-sjB.w);
        *(float4*)&Dt[row][tx*4]      = vA;
        *(float4*)&Dt[row][64 + tx*4] = vB;
      }
    }
    __syncthreads();
    // ---- selection: wave wv scans rows wv*16..wv*16+15 (R2-proven insert) ----
#pragma unroll
    for (int rr = 0; rr < 16; ++rr){
      const int row = wv*16 + rr;
      float v0 = Dt[row][lane];
      float v1 = Dt[row][64 + lane];
      float thr = __shfl(lv[rr], KNN-1);
      unsigned long long mask = __ballot(v0 > thr);
      while (mask){
        int l = __ffsll((unsigned long long)mask) - 1;
        mask &= mask - 1;
        float dv = __shfl(v0, l);
        if (dv > thr){
          float upv = __shfl_up(lv[rr], 1);
          int   upi = __shfl_up(li[rr], 1);
          if (lane < KNN){
            bool ins  = dv > lv[rr];
            bool insp = (lane > 0) && (dv > upv);
            if (ins){ lv[rr] = insp ? upv : dv; li[rr] = insp ? upi : (j0 + l); }
          }
          thr = __shfl(lv[rr], KNN-1);
        }
      }
      mask = __ballot(v1 > thr);
      while (mask){
        int l = __ffsll((unsigned long long)mask) - 1;
        mask &= mask - 1;
        float dv = __shfl(v1, l);
        if (dv > thr){
          float upv = __shfl_up(lv[rr], 1);
          int   upi = __shfl_up(li[rr], 1);
          if (lane < KNN){
            bool ins  = dv > lv[rr];
            bool insp = (lane > 0) && (dv > upv);
            if (ins){ lv[rr] = insp ? upv : dv; li[rr] = insp ? upi : (j0 + 64 + l); }
          }
          thr = __shfl(lv[rr], KNN-1);
        }
      }
    }
    __syncthreads();
  }
#pragma unroll
  for (int rr = 0; rr < 16; ++rr){
    if (lane < KNN){
      int gn = b*NPTS + i0 + wv*16 + rr;
      cand_v[((size_t)gn*NSPL + sp)*KNN + lane] = lv[rr];
      cand_i[((size_t)gn*NSPL + sp)*KNN + lane] = li[rr];
    }
  }
}

// merge NSPL per-split sorted top-20 lists -> final top-20 per row.
// splits ascending (ascending col ranges) + strict > insert: stable tie-break.
__global__ __launch_bounds__(256) void k_knn_merge(const float* __restrict__ cand_v,
                                                   const int* __restrict__ cand_i,
                                                   int* __restrict__ idx){
  int gn = blockIdx.x*256 + threadIdx.x;
  float bv[KNN]; int bi[KNN];
#pragma unroll
  for (int j = 0; j < KNN; ++j){ bv[j] = -3e38f; bi[j] = -1; }
  for (int s = 0; s < NSPL; ++s){
#pragma unroll 1
    for (int t = 0; t < KNN; ++t){
      float d  = cand_v[((size_t)gn*NSPL + s)*KNN + t];
      int   mi = cand_i[((size_t)gn*NSPL + s)*KNN + t];
      if (d > bv[KNN-1]) topk_insert(bv, bi, d, mi);
    }
  }
#pragma unroll
  for (int j = 0; j < KNN; ++j) idx[(size_t)gn*KNN + j] = bi[j];
}

// PQ(M x 2*Och) = X(M x Kdim) @ [Wa; Wb]^T where Wa=W[:, :Kdim], Wb=W[:, Kdim:2Kdim].
// BM=128, BO=64, BK=16, 8x4 micro.
__global__ __launch_bounds__(256) void k_gemm_pq(const float* __restrict__ X, int xstride, int Kdim,
                                                 const float* __restrict__ W, int wstride, int Och,
                                                 float* __restrict__ PQ){
  __shared__ float Xs[16][132];
  __shared__ float Ws[16][68];
  const int m0 = blockIdx.x*128, o0 = blockIdx.y*64;
  const int tid = threadIdx.x, tx = tid & 15, ty = tid >> 4;
  const int O2 = 2*Och;
  float acc[8][4] = {};
  for (int k0 = 0; k0 < Kdim; k0 += 16){
#pragma unroll
    for (int i = 0; i < 8; ++i){
      int li = tid + 256*i;
      int row = li >> 4, kk = li & 15;
      bool ok = (k0 + kk) < Kdim;
      Xs[kk][row] = ok ? X[(size_t)(m0+row)*xstride + k0+kk] : 0.f;
    }
#pragma unroll
    for (int i = 0; i < 4; ++i){
      int li = tid + 256*i;
      int row = li >> 4, kk = li & 15;
      int orow = o0 + row;
      const float* wr = (orow < Och) ? (W + (size_t)orow*wstride)
                                     : (W + (size_t)(orow-Och)*wstride + Kdim);
      bool ok = (k0 + kk) < Kdim;
      Ws[kk][row] = ok ? wr[k0+kk] : 0.f;
    }
    __syncthreads();
#pragma unroll
    for (int kk = 0; kk < 16; ++kk){
      float xa[8], wb[4];
      *(float4*)&xa[0] = *(const float4*)&Xs[kk][ty*8];
      *(float4*)&xa[4] = *(const float4*)&Xs[kk][ty*8+4];
      *(float4*)wb     = *(const float4*)&Ws[kk][tx*4];
#pragma unroll
      for (int i = 0; i < 8; ++i)
#pragma unroll
        for (int j = 0; j < 4; ++j)
          acc[i][j] = fmaf(xa[i], wb[j], acc[i][j]);
    }
    __syncthreads();
  }
#pragma unroll
  for (int i = 0; i < 8; ++i){
    float4 v = make_float4(acc[i][0], acc[i][1], acc[i][2], acc[i][3]);
    *(float4*)&PQ[(size_t)(m0+ty*8+i)*O2 + o0 + tx*4] = v;
  }
}

// out[n,o] = lrelu(scale*(red_k P[mk,o] - P[n,o] + Q[n,o]) + beta); red=max if scale>=0 else min
// P(m,o) = PQ[m*2O + o]; Q(n,o) = PQ[n*2O + O + o]
__global__ __launch_bounds__(256) void k_gather_conv(const float* __restrict__ PQ,
                                                     const int* __restrict__ idx,
                                                     const float* __restrict__ g,
                                                     const float* __restrict__ bb,
                                                     const float* __restrict__ rm,
                                                     const float* __restrict__ rv,
                                                     float* __restrict__ Out, int oshift, int choff){
  const int O = 1 << oshift;
  int id = blockIdx.x*256 + threadIdx.x;
  int gn = id >> oshift;
  int o  = id & (O-1);
  int bbase = (gn >> 12) * NPTS;
  const int* ip = idx + (size_t)gn*KNN;
  float vmax = -3e38f, vmin = 3e38f;
#pragma unroll
  for (int k = 0; k < KNN; ++k){
    int m = ip[k];
    float v = PQ[((size_t)(bbase + m) << (oshift+1)) + o];
    vmax = fmaxf(vmax, v);
    vmin = fminf(vmin, v);
  }
  float scale = g[o] * rsqrtf(rv[o] + EPSBN);
  float beta  = bb[o] - rm[o]*scale;
  float R = (scale >= 0.f) ? vmax : vmin;
  size_t self = (size_t)gn << (oshift+1);
  float h = R - PQ[self + o] + PQ[self + O + o];
  Out[(size_t)gn*512 + choff + o] = lrelu(fmaf(scale, h, beta));
}

// h = lrelu(bn(xc @ W5^T)) tile (128x128, 8x8 micro, split col groups),
// fused partial max/sum over rows.
__global__ __launch_bounds__(256) void k_gemm_w5_pool(const float* __restrict__ X,
                                                      const float* __restrict__ W,
                                                      const float* __restrict__ g,
                                                      const float* __restrict__ bb,
                                                      const float* __restrict__ rm,
                                                      const float* __restrict__ rv,
                                                      float* __restrict__ pmax,
                                                      float* __restrict__ psum){
  __shared__ float Xs[16][132];
  __shared__ float Ws[16][132];
  __shared__ float red[2][16][128];
  const int m0 = blockIdx.x*128, o0 = blockIdx.y*128;
  const int tid = threadIdx.x, tx = tid & 15, ty = tid >> 4;
  float acc[8][8] = {};
  for (int k0 = 0; k0 < 512; k0 += 16){
#pragma unroll
    for (int i = 0; i < 8; ++i){
      int li = tid + 256*i;
      int row = li >> 4, kk = li & 15;
      Xs[kk][row] = X[(size_t)(m0+row)*512 + k0+kk];
      Ws[kk][row] = W[(size_t)(o0+row)*512 + k0+kk];
    }
    __syncthreads();
#pragma unroll
    for (int kk = 0; kk < 16; ++kk){
      float xa[8], wb[8];
      *(float4*)&xa[0] = *(const float4*)&Xs[kk][ty*8];
      *(float4*)&xa[4] = *(const float4*)&Xs[kk][ty*8+4];
      *(float4*)&wb[0] = *(const float4*)&Ws[kk][tx*4];
      *(float4*)&wb[4] = *(const float4*)&Ws[kk][64 + tx*4];
#pragma unroll
      for (int i = 0; i < 8; ++i)
#pragma unroll
        for (int j = 0; j < 8; ++j)
          acc[i][j] = fmaf(xa[i], wb[j], acc[i][j]);
    }
    __syncthreads();
  }
#pragma unroll
  for (int j = 0; j < 8; ++j){
    int ocol = (j < 4) ? (tx*4 + j) : (64 + tx*4 + j - 4);
    int o = o0 + ocol;
    float scale = g[o] * rsqrtf(rv[o] + EPSBN);
    float beta  = bb[o] - rm[o]*scale;
    float mx = -3e38f, sm = 0.f;
#pragma unroll
    for (int i = 0; i < 8; ++i){
      float h = lrelu(fmaf(scale, acc[i][j], beta));
      mx = fmaxf(mx, h);
      sm += h;
    }
    red[0][ty][ocol] = mx;
    red[1][ty][ocol] = sm;
  }
  __syncthreads();
  if (tid < 128){
    float mx = -3e38f, sm = 0.f;
#pragma unroll
    for (int t = 0; t < 16; ++t){
      mx = fmaxf(mx, red[0][t][tid]);
      sm += red[1][t][tid];
    }
    pmax[(size_t)blockIdx.x*1024 + o0 + tid] = mx;
    psum[(size_t)blockIdx.x*1024 + o0 + tid] = sm;
  }
}

__global__ __launch_bounds__(256) void k_pool_reduce(const float* __restrict__ pmax,
                                                     const float* __restrict__ psum,
                                                     float* __restrict__ pooled){
  int id = blockIdx.x*256 + threadIdx.x;   // 8192
  int b = id >> 10, o = id & 1023;
  float mx = -3e38f, sm = 0.f;
  for (int t = 0; t < 32; ++t){
    mx = fmaxf(mx, pmax[(size_t)(b*32+t)*1024 + o]);
    sm += psum[(size_t)(b*32+t)*1024 + o];
  }
  pooled[(size_t)b*2048 + o] = mx;
  pooled[(size_t)b*2048 + 1024 + o] = sm * (1.f/NPTS);
}

__global__ __launch_bounds__(256) void k_fc1(const float* __restrict__ pooled,
                                             const float* __restrict__ W,
                                             const float* __restrict__ g,
                                             const float* __restrict__ bb,
                                             const float* __restrict__ rm,
                                             const float* __restrict__ rv,
                                             float* __restrict__ out){
  __shared__ float4 xs[512];
  int b = blockIdx.x >> 1;
  int o = ((blockIdx.x & 1) << 8) + threadIdx.x;
  const float4* pr = (const float4*)(pooled + (size_t)b*2048);
  for (int l = threadIdx.x; l < 512; l += 256) xs[l] = pr[l];
  __syncthreads();
  const float4* wr = (const float4*)(W + (size_t)o*2048);
  float s0=0.f, s1=0.f, s2=0.f, s3=0.f;
#pragma unroll 4
  for (int c = 0; c < 512; ++c){
    float4 w = wr[c], v = xs[c];
    s0 = fmaf(v.x, w.x, s0); s1 = fmaf(v.y, w.y, s1);
    s2 = fmaf(v.z, w.z, s2); s3 = fmaf(v.w, w.w, s3);
  }
  float h = (s0+s1)+(s2+s3);
  float scale = g[o] * rsqrtf(rv[o] + EPSBN);
  float beta  = bb[o] - rm[o]*scale;
  out[(size_t)b*512 + o] = lrelu(fmaf(scale, h, beta));
}

__global__ __launch_bounds__(256) void k_fc2(const float* __restrict__ in,
                                             const float* __restrict__ W,
                                             const float* __restrict__ bias,
                                             const float* __restrict__ g,
                                             const float* __restrict__ bb,
                                             const float* __restrict__ rm,
                                             const float* __restrict__ rv,
                                             float* __restrict__ out){
  __shared__ float4 xs[128];
  int b = blockIdx.x;
  int o = threadIdx.x;
  const float4* pr = (const float4*)(in + (size_t)b*512);
  if (threadIdx.x < 128) xs[threadIdx.x] = pr[threadIdx.x];
  __syncthreads();
  const float4* wr = (const float4*)(W + (size_t)o*512);
  float s0=0.f, s1=0.f, s2=0.f, s3=0.f;
#pragma unroll 4
  for (int c = 0; c < 128; ++c){
    float4 w = wr[c], v = xs[c];
    s0 = fmaf(v.x, w.x, s0); s1 = fmaf(v.y, w.y, s1);
    s2 = fmaf(v.z, w.z, s2); s3 = fmaf(v.w, w.w, s3);
  }
  float h = (s0+s1)+(s2+s3) + bias[o];
  float scale = g[o] * rsqrtf(rv[o] + EPSBN);
  float beta  = bb[o] - rm[o]*scale;
  out[(size_t)b*256 + o] = lrelu(fmaf(scale, h, beta));
}

__global__ __launch_bounds__(64) void k_fc3(const float* __restrict__ in,
                                            const float* __restrict__ W,
                                            const float* __restrict__ bias,
                                            float* __restrict__ out){
  int t = threadIdx.x;
  if (t >= 16) return;
  int b = t >> 1, o = t & 1;
  const float* xr = in + (size_t)b*256;
  const float* wr = W + (size_t)o*256;
  float s = 0.f;
  for (int c = 0; c < 256; ++c) s = fmaf(xr[c], wr[c], s);
  out[b*2 + o] = s + bias[o];
}

extern "C" void kernel_launch(void* const* d_in, const int* in_sizes, int n_in,
                              void* d_out, int out_size, void* d_ws, size_t ws_size,
                              hipStream_t stream){
  (void)in_sizes; (void)n_in; (void)out_size;
  const float* x   = (const float*)d_in[0];
  const float* W1  = (const float*)d_in[1];
  const float* g1  = (const float*)d_in[2];
  const float* b1  = (const float*)d_in[3];
  const float* m1  = (const float*)d_in[4];
  const float* v1  = (const float*)d_in[5];
  const float* W2  = (const float*)d_in[6];
  const float* g2  = (const float*)d_in[7];
  const float* b2  = (const float*)d_in[8];
  const float* m2  = (const float*)d_in[9];
  const float* v2  = (const float*)d_in[10];
  const float* W3  = (const float*)d_in[11];
  const float* g3  = (const float*)d_in[12];
  const float* b3  = (const float*)d_in[13];
  const float* m3  = (const float*)d_in[14];
  const float* v3  = (const float*)d_in[15];
  const float* W4  = (const float*)d_in[16];
  const float* g4  = (const float*)d_in[17];
  const float* b4  = (const float*)d_in[18];
  const float* m4  = (const float*)d_in[19];
  const float* v4  = (const float*)d_in[20];
  const float* W5  = (const float*)d_in[21];
  const float* g5  = (const float*)d_in[22];
  const float* b5  = (const float*)d_in[23];
  const float* m5  = (const float*)d_in[24];
  const float* v5  = (const float*)d_in[25];
  const float* L1  = (const float*)d_in[26];
  const float* gl1 = (const float*)d_in[27];
  const float* bl1 = (const float*)d_in[28];
  const float* ml1 = (const float*)d_in[29];
  const float* vl1 = (const float*)d_in[30];
  const float* L2  = (const float*)d_in[31];
  const float* L2b = (const float*)d_in[32];
  const float* gl2 = (const float*)d_in[33];
  const float* bl2 = (const float*)d_in[34];
  const float* ml2 = (const float*)d_in[35];
  const float* vl2 = (const float*)d_in[36];
  const float* L3  = (const float*)d_in[37];
  const float* L3b = (const float*)d_in[38];

  // workspace layout (float offsets)
  float* ws    = (float*)d_ws;
  float* xt    = ws;                      //   262144
  float* sq    = ws + 262144;             //    32768
  int*   idx   = (int*)(ws + 294912);     //   655360 ints
  float* candv = ws + 950272;             //  (BNR*NSPL*20) = 1310720
  int*   candi = (int*)(ws + 3571712);    //  ditto
  float* PQ    = ws + 6193152;            // 16777216 (max: 32768 x 512)
  float* xc    = ws + 22970368;           // 16777216  (8,4096,512) concat x1..x4
  float* pmax  = ws + 39747584;           //   262144
  float* psum  = ws + 40009728;           //   262144
  float* pool  = ws + 40271872;           //    16384
  float* oA    = ws + 40288256;           //     4096
  float* oB    = ws + 40292352;           //     2048
  if (ws_size < (size_t)40294400 * 4) return;  // ~161 MB scratch

  k_transpose_pad<<<128, 256, 0, stream>>>(x, xt);

  // ---- edge conv 1: in xt (C=6 padded to 8), out xc[:,:,0:64] ----
  k_sqnorm<<<128, 256, 0, stream>>>(xt, 8, 2, sq);
  k_knn_fused<8><<<dim3(64,NSPL,8), 256, 0, stream>>>(xt, 8, sq, candv, candi);
  k_knn_merge<<<128, 256, 0, stream>>>(candv, candi, idx);
  k_gemm_pq<<<dim3(256,2), 256, 0, stream>>>(xt, 8, 6, W1, 12, 64, PQ);
  k_gather_conv<<<8192, 256, 0, stream>>>(PQ, idx, g1, b1, m1, v1, xc, 6, 0);

  // ---- edge conv 2: in xc[:,:,0:64], out xc[:,:,64:128] ----
  k_sqnorm<<<128, 256, 0, stream>>>(xc, 512, 16, sq);
  k_knn_fused<64><<<dim3(64,NSPL,8), 256, 0, stream>>>(xc, 512, sq, candv, candi);
  k_knn_merge<<<128, 256, 0, stream>>>(candv, candi, idx);
  k_gemm_pq<<<dim3(256,2), 256, 0, stream>>>(xc, 512, 64, W2, 128, 64, PQ);
  k_gather_conv<<<8192, 256, 0, stream>>>(PQ, idx, g2, b2, m2, v2, xc, 6, 64);

  // ---- edge conv 3: in xc[:,:,64:128], out xc[:,:,128:256] ----
  k_sqnorm<<<128, 256, 0, stream>>>(xc + 64, 512, 16, sq);
  k_knn_fused<64><<<dim3(64,NSPL,8), 256, 0, stream>>>(xc + 64, 512, sq, candv, candi);
  k_knn_merge<<<128, 256, 0, stream>>>(candv, candi, idx);
  k_gemm_pq<<<dim3(256,4), 256, 0, stream>>>(xc + 64, 512, 64, W3, 128, 128, PQ);
  k_gather_conv<<<16384, 256, 0, stream>>>(PQ, idx, g3, b3, m3, v3, xc, 7, 128);

  // ---- edge conv 4: in xc[:,:,128:256], out xc[:,:,256:512] ----
  k_sqnorm<<<128, 256, 0, stream>>>(xc + 128, 512, 32, sq);
  k_knn_fused<128><<<dim3(64,NSPL,8), 256, 0, stream>>>(xc + 128, 512, sq, candv, candi);
  k_knn_merge<<<128, 256, 0, stream>>>(candv, candi, idx);
  k_gemm_pq<<<dim3(256,8), 256, 0, stream>>>(xc + 128, 512, 128, W4, 256, 256, PQ);
  k_gather_conv<<<32768, 256, 0, stream>>>(PQ, idx, g4, b4, m4, v4, xc, 8, 256);

  // ---- global feature: h = lrelu(bn(xc @ W5^T)), max+mean pool over N ----
  k_gemm_w5_pool<<<dim3(256,8), 256, 0, stream>>>(xc, W5, g5, b5, m5, v5, pmax, psum);
  k_pool_reduce<<<32, 256, 0, stream>>>(pmax, psum, pool);

  // ---- classifier head ----
  k_fc1<<<16, 256, 0, stream>>>(pool, L1, gl1, bl1, ml1, vl1, oA);
  k_fc2<<<8, 256, 0, stream>>>(oA, L2, L2b, gl2, bl2, ml2, vl2, oB);
  k_fc3<<<1, 64, 0, stream>>>(oB, L3, L3b, (float*)d_out);
}

// Round 10
// 3700.873 us; speedup vs baseline: 1.9564x; 1.1837x over previous
//
#include <hip/hip_runtime.h>

// DGCNN forward, fp32 throughout.
// R10: kNN split into two PROVEN single-purpose kernels (fused variants R4-R9
// all lose to this on measured counters):
//   k_dgemm: per-batch distance GEMM, w5-core (128x128 tile, 8x8 micro, split
//            col groups tx*4 / 64+tx*4, stride-132 LDS -> conflict-free, 79TF).
//   k_scan:  R2-proven wave-per-row ballot/shfl top-20, float4 loads (4x fewer
//            ballot rounds). D (64MB/batch) stays L2/L3-resident, aliases PQ.
// No NSPL splits, no merge kernel, no atomics, no candidate buffers.

#define NPTS   4096
#define NB     8
#define BNR    32768      // NB*NPTS
#define KNN    20
#define EPSBN  1e-5f

__device__ __forceinline__ float lrelu(float x){ return x > 0.f ? x : 0.2f*x; }

// x (8,6,4096) -> xt (8,4096,8), channels 6,7 zero-padded
__global__ __launch_bounds__(256) void k_transpose_pad(const float* __restrict__ x,
                                                       float* __restrict__ xt){
  int id = blockIdx.x*256 + threadIdx.x;          // 0..32767
  int b = id >> 12, n = id & (NPTS-1);
  const float* xb = x + (size_t)b*6*NPTS + n;
  float* o = xt + (size_t)id*8;
#pragma unroll
  for (int c = 0; c < 6; ++c) o[c] = xb[(size_t)c*NPTS];
  o[6] = 0.f; o[7] = 0.f;
}

// squared norm per row (c4 float4 groups, row stride xstride floats)
__global__ __launch_bounds__(256) void k_sqnorm(const float* __restrict__ X, int xstride, int c4,
                                                float* __restrict__ sq){
  int id = blockIdx.x*256 + threadIdx.x;
  const float4* r = (const float4*)(X + (size_t)id*xstride);
  float s = 0.f;
  for (int c = 0; c < c4; ++c){ float4 v = r[c]; s += v.x*v.x + v.y*v.y + v.z*v.z + v.w*v.w; }
  sq[id] = s;
}

// D[i][j] = 2*dot(x_i,x_j) - sq_i - sq_j for one batch. 128x128 tile, 8x8 micro,
// conflict-free (rows ty*8+r; col groups tx*4+c and 64+tx*4+c; LDS stride 132).
__global__ __launch_bounds__(256) void k_dgemm(const float* __restrict__ X, int xstride, int Kdim,
                                               const float* __restrict__ sqv,
                                               float* __restrict__ D){
  __shared__ float As[16][132];
  __shared__ float Bs[16][132];
  const int i0 = blockIdx.y*128, j0 = blockIdx.x*128;
  const int tid = threadIdx.x, tx = tid & 15, ty = tid >> 4;
  float acc[8][8] = {};
  for (int k0 = 0; k0 < Kdim; k0 += 16){
#pragma unroll
    for (int i = 0; i < 8; ++i){
      int li = tid + 256*i;
      int row = li >> 4, kk = li & 15;
      bool ok = (k0 + kk) < Kdim;
      As[kk][row] = ok ? X[(size_t)(i0+row)*xstride + k0+kk] : 0.f;
      Bs[kk][row] = ok ? X[(size_t)(j0+row)*xstride + k0+kk] : 0.f;
    }
    __syncthreads();
#pragma unroll
    for (int kk = 0; kk < 16; ++kk){
      float a[8], b[8];
      *(float4*)&a[0] = *(const float4*)&As[kk][ty*8];
      *(float4*)&a[4] = *(const float4*)&As[kk][ty*8+4];
      *(float4*)&b[0] = *(const float4*)&Bs[kk][tx*4];
      *(float4*)&b[4] = *(const float4*)&Bs[kk][64 + tx*4];
#pragma unroll
      for (int r = 0; r < 8; ++r)
#pragma unroll
        for (int c = 0; c < 8; ++c)
          acc[r][c] = fmaf(a[r], b[c], acc[r][c]);
    }
    __syncthreads();
  }
  float si[8], sj[8];
#pragma unroll
  for (int r = 0; r < 8; ++r) si[r] = sqv[i0 + ty*8 + r];
#pragma unroll
  for (int c = 0; c < 4; ++c){
    sj[c]   = sqv[j0 + tx*4 + c];
    sj[c+4] = sqv[j0 + 64 + tx*4 + c];
  }
#pragma unroll
  for (int r = 0; r < 8; ++r){
    float* drow = D + (size_t)(i0 + ty*8 + r)*NPTS;
    *(float4*)&drow[j0 + tx*4] =
      make_float4(2.f*acc[r][0]-si[r]-sj[0], 2.f*acc[r][1]-si[r]-sj[1],
                  2.f*acc[r][2]-si[r]-sj[2], 2.f*acc[r][3]-si[r]-sj[3]);
    *(float4*)&drow[j0 + 64 + tx*4] =
      make_float4(2.f*acc[r][4]-si[r]-sj[4], 2.f*acc[r][5]-si[r]-sj[5],
                  2.f*acc[r][6]-si[r]-sj[6], 2.f*acc[r][7]-si[r]-sj[7]);
  }
}

// one wave per row: top-20 (value desc, tie -> lower index) in lanes 0..19.
// float4 loads: 256 cols per ballot round, 16 rounds per row.
__global__ __launch_bounds__(256) void k_scan(const float* __restrict__ D,
                                              int* __restrict__ idx){
  const int lane = threadIdx.x & 63;
  const int wv   = threadIdx.x >> 6;
  const int row  = blockIdx.x*4 + wv;             // 0..4095 within batch
  const float4* drow = (const float4*)(D + (size_t)row*NPTS);
  float lv = -3e38f; int li = 0;
  float thr = -3e38f;
  float4 cur = drow[lane];
  for (int m0 = 0; m0 < NPTS; m0 += 256){
    float4 nxt = make_float4(-3e38f,-3e38f,-3e38f,-3e38f);
    if (m0 + 256 < NPTS) nxt = drow[((m0+256) >> 2) + lane];
    float mx4 = fmaxf(fmaxf(cur.x, cur.y), fmaxf(cur.z, cur.w));
    unsigned long long mask = __ballot(mx4 > thr);
    while (mask){
      int l = __ffsll(mask) - 1;
      mask &= mask - 1;
      float v0 = __shfl(cur.x, l);
      float v1 = __shfl(cur.y, l);
      float v2 = __shfl(cur.z, l);
      float v3 = __shfl(cur.w, l);
      int c0 = m0 + 4*l;
#pragma unroll
      for (int j = 0; j < 4; ++j){
        float dv = (j==0) ? v0 : (j==1) ? v1 : (j==2) ? v2 : v3;
        if (dv > thr){
          float upv = __shfl_up(lv, 1);
          int   upi = __shfl_up(li, 1);
          if (lane < KNN){
            bool ins  = dv > lv;                  // list sorted desc
            bool insp = (lane > 0) && (dv > upv);
            if (ins){ lv = insp ? upv : dv; li = insp ? upi : (c0 + j); }
          }
          thr = __shfl(lv, KNN-1);
        }
      }
    }
    cur = nxt;
  }
  if (lane < KNN) idx[(size_t)row*KNN + lane] = li;
}

// PQ(M x 2*Och) = X(M x Kdim) @ [Wa; Wb]^T where Wa=W[:, :Kdim], Wb=W[:, Kdim:2Kdim].
// BM=128, BO=64, BK=16, 8x4 micro.
__global__ __launch_bounds__(256) void k_gemm_pq(const float* __restrict__ X, int xstride, int Kdim,
                                                 const float* __restrict__ W, int wstride, int Och,
                                                 float* __restrict__ PQ){
  __shared__ float Xs[16][132];
  __shared__ float Ws[16][68];
  const int m0 = blockIdx.x*128, o0 = blockIdx.y*64;
  const int tid = threadIdx.x, tx = tid & 15, ty = tid >> 4;
  const int O2 = 2*Och;
  float acc[8][4] = {};
  for (int k0 = 0; k0 < Kdim; k0 += 16){
#pragma unroll
    for (int i = 0; i < 8; ++i){
      int li = tid + 256*i;
      int row = li >> 4, kk = li & 15;
      bool ok = (k0 + kk) < Kdim;
      Xs[kk][row] = ok ? X[(size_t)(m0+row)*xstride + k0+kk] : 0.f;
    }
#pragma unroll
    for (int i = 0; i < 4; ++i){
      int li = tid + 256*i;
      int row = li >> 4, kk = li & 15;
      int orow = o0 + row;
      const float* wr = (orow < Och) ? (W + (size_t)orow*wstride)
                                     : (W + (size_t)(orow-Och)*wstride + Kdim);
      bool ok = (k0 + kk) < Kdim;
      Ws[kk][row] = ok ? wr[k0+kk] : 0.f;
    }
    __syncthreads();
#pragma unroll
    for (int kk = 0; kk < 16; ++kk){
      float xa[8], wb[4];
      *(float4*)&xa[0] = *(const float4*)&Xs[kk][ty*8];
      *(float4*)&xa[4] = *(const float4*)&Xs[kk][ty*8+4];
      *(float4*)wb     = *(const float4*)&Ws[kk][tx*4];
#pragma unroll
      for (int i = 0; i < 8; ++i)
#pragma unroll
        for (int j = 0; j < 4; ++j)
          acc[i][j] = fmaf(xa[i], wb[j], acc[i][j]);
    }
    __syncthreads();
  }
#pragma unroll
  for (int i = 0; i < 8; ++i){
    float4 v = make_float4(acc[i][0], acc[i][1], acc[i][2], acc[i][3]);
    *(float4*)&PQ[(size_t)(m0+ty*8+i)*O2 + o0 + tx*4] = v;
  }
}

// out[n,o] = lrelu(scale*(red_k P[mk,o] - P[n,o] + Q[n,o]) + beta); red=max if scale>=0 else min
// P(m,o) = PQ[m*2O + o]; Q(n,o) = PQ[n*2O + O + o]
__global__ __launch_bounds__(256) void k_gather_conv(const float* __restrict__ PQ,
                                                     const int* __restrict__ idx,
                                                     const float* __restrict__ g,
                                                     const float* __restrict__ bb,
                                                     const float* __restrict__ rm,
                                                     const float* __restrict__ rv,
                                                     float* __restrict__ Out, int oshift, int choff){
  const int O = 1 << oshift;
  int id = blockIdx.x*256 + threadIdx.x;
  int gn = id >> oshift;
  int o  = id & (O-1);
  int bbase = (gn >> 12) * NPTS;
  const int* ip = idx + (size_t)gn*KNN;
  float vmax = -3e38f, vmin = 3e38f;
#pragma unroll
  for (int k = 0; k < KNN; ++k){
    int m = ip[k];
    float v = PQ[((size_t)(bbase + m) << (oshift+1)) + o];
    vmax = fmaxf(vmax, v);
    vmin = fminf(vmin, v);
  }
  float scale = g[o] * rsqrtf(rv[o] + EPSBN);
  float beta  = bb[o] - rm[o]*scale;
  float R = (scale >= 0.f) ? vmax : vmin;
  size_t self = (size_t)gn << (oshift+1);
  float h = R - PQ[self + o] + PQ[self + O + o];
  Out[(size_t)gn*512 + choff + o] = lrelu(fmaf(scale, h, beta));
}

// h = lrelu(bn(xc @ W5^T)) tile (128x128, 8x8 micro, split col groups),
// fused partial max/sum over rows.
__global__ __launch_bounds__(256) void k_gemm_w5_pool(const float* __restrict__ X,
                                                      const float* __restrict__ W,
                                                      const float* __restrict__ g,
                                                      const float* __restrict__ bb,
                                                      const float* __restrict__ rm,
                                                      const float* __restrict__ rv,
                                                      float* __restrict__ pmax,
                                                      float* __restrict__ psum){
  __shared__ float Xs[16][132];
  __shared__ float Ws[16][132];
  __shared__ float red[2][16][128];
  const int m0 = blockIdx.x*128, o0 = blockIdx.y*128;
  const int tid = threadIdx.x, tx = tid & 15, ty = tid >> 4;
  float acc[8][8] = {};
  for (int k0 = 0; k0 < 512; k0 += 16){
#pragma unroll
    for (int i = 0; i < 8; ++i){
      int li = tid + 256*i;
      int row = li >> 4, kk = li & 15;
      Xs[kk][row] = X[(size_t)(m0+row)*512 + k0+kk];
      Ws[kk][row] = W[(size_t)(o0+row)*512 + k0+kk];
    }
    __syncthreads();
#pragma unroll
    for (int kk = 0; kk < 16; ++kk){
      float xa[8], wb[8];
      *(float4*)&xa[0] = *(const float4*)&Xs[kk][ty*8];
      *(float4*)&xa[4] = *(const float4*)&Xs[kk][ty*8+4];
      *(float4*)&wb[0] = *(const float4*)&Ws[kk][tx*4];
      *(float4*)&wb[4] = *(const float4*)&Ws[kk][64 + tx*4];
#pragma unroll
      for (int i = 0; i < 8; ++i)
#pragma unroll
        for (int j = 0; j < 8; ++j)
          acc[i][j] = fmaf(xa[i], wb[j], acc[i][j]);
    }
    __syncthreads();
  }
#pragma unroll
  for (int j = 0; j < 8; ++j){
    int ocol = (j < 4) ? (tx*4 + j) : (64 + tx*4 + j - 4);
    int o = o0 + ocol;
    float scale = g[o] * rsqrtf(rv[o] + EPSBN);
    float beta  = bb[o] - rm[o]*scale;
    float mx = -3e38f, sm = 0.f;
#pragma unroll
    for (int i = 0; i < 8; ++i){
      float h = lrelu(fmaf(scale, acc[i][j], beta));
      mx = fmaxf(mx, h);
      sm += h;
    }
    red[0][ty][ocol] = mx;
    red[1][ty][ocol] = sm;
  }
  __syncthreads();
  if (tid < 128){
    float mx = -3e38f, sm = 0.f;
#pragma unroll
    for (int t = 0; t < 16; ++t){
      mx = fmaxf(mx, red[0][t][tid]);
      sm += red[1][t][tid];
    }
    pmax[(size_t)blockIdx.x*1024 + o0 + tid] = mx;
    psum[(size_t)blockIdx.x*1024 + o0 + tid] = sm;
  }
}

__global__ __launch_bounds__(256) void k_pool_reduce(const float* __restrict__ pmax,
                                                     const float* __restrict__ psum,
                                                     float* __restrict__ pooled){
  int id = blockIdx.x*256 + threadIdx.x;   // 8192
  int b = id >> 10, o = id & 1023;
  float mx = -3e38f, sm = 0.f;
  for (int t = 0; t < 32; ++t){
    mx = fmaxf(mx, pmax[(size_t)(b*32+t)*1024 + o]);
    sm += psum[(size_t)(b*32+t)*1024 + o];
  }
  pooled[(size_t)b*2048 + o] = mx;
  pooled[(size_t)b*2048 + 1024 + o] = sm * (1.f/NPTS);
}

__global__ __launch_bounds__(256) void k_fc1(const float* __restrict__ pooled,
                                             const float* __restrict__ W,
                                             const float* __restrict__ g,
                                             const float* __restrict__ bb,
                                             const float* __restrict__ rm,
                                             const float* __restrict__ rv,
                                             float* __restrict__ out){
  __shared__ float4 xs[512];
  int b = blockIdx.x >> 1;
  int o = ((blockIdx.x & 1) << 8) + threadIdx.x;
  const float4* pr = (const float4*)(pooled + (size_t)b*2048);
  for (int l = threadIdx.x; l < 512; l += 256) xs[l] = pr[l];
  __syncthreads();
  const float4* wr = (const float4*)(W + (size_t)o*2048);
  float s0=0.f, s1=0.f, s2=0.f, s3=0.f;
#pragma unroll 4
  for (int c = 0; c < 512; ++c){
    float4 w = wr[c], v = xs[c];
    s0 = fmaf(v.x, w.x, s0); s1 = fmaf(v.y, w.y, s1);
    s2 = fmaf(v.z, w.z, s2); s3 = fmaf(v.w, w.w, s3);
  }
  float h = (s0+s1)+(s2+s3);
  float scale = g[o] * rsqrtf(rv[o] + EPSBN);
  float beta  = bb[o] - rm[o]*scale;
  out[(size_t)b*512 + o] = lrelu(fmaf(scale, h, beta));
}

__global__ __launch_bounds__(256) void k_fc2(const float* __restrict__ in,
                                             const float* __restrict__ W,
                                             const float* __restrict__ bias,
                                             const float* __restrict__ g,
                                             const float* __restrict__ bb,
                                             const float* __restrict__ rm,
                                             const float* __restrict__ rv,
                                             float* __restrict__ out){
  __shared__ float4 xs[128];
  int b = blockIdx.x;
  int o = threadIdx.x;
  const float4* pr = (const float4*)(in + (size_t)b*512);
  if (threadIdx.x < 128) xs[threadIdx.x] = pr[threadIdx.x];
  __syncthreads();
  const float4* wr = (const float4*)(W + (size_t)o*512);
  float s0=0.f, s1=0.f, s2=0.f, s3=0.f;
#pragma unroll 4
  for (int c = 0; c < 128; ++c){
    float4 w = wr[c], v = xs[c];
    s0 = fmaf(v.x, w.x, s0); s1 = fmaf(v.y, w.y, s1);
    s2 = fmaf(v.z, w.z, s2); s3 = fmaf(v.w, w.w, s3);
  }
  float h = (s0+s1)+(s2+s3) + bias[o];
  float scale = g[o] * rsqrtf(rv[o] + EPSBN);
  float beta  = bb[o] - rm[o]*scale;
  out[(size_t)b*256 + o] = lrelu(fmaf(scale, h, beta));
}

__global__ __launch_bounds__(64) void k_fc3(const float* __restrict__ in,
                                            const float* __restrict__ W,
                                            const float* __restrict__ bias,
                                            float* __restrict__ out){
  int t = threadIdx.x;
  if (t >= 16) return;
  int b = t >> 1, o = t & 1;
  const float* xr = in + (size_t)b*256;
  const float* wr = W + (size_t)o*256;
  float s = 0.f;
  for (int c = 0; c < 256; ++c) s = fmaf(xr[c], wr[c], s);
  out[b*2 + o] = s + bias[o];
}

extern "C" void kernel_launch(void* const* d_in, const int* in_sizes, int n_in,
                              void* d_out, int out_size, void* d_ws, size_t ws_size,
                              hipStream_t stream){
  (void)in_sizes; (void)n_in; (void)out_size;
  const float* x   = (const float*)d_in[0];
  const float* W1  = (const float*)d_in[1];
  const float* g1  = (const float*)d_in[2];
  const float* b1  = (const float*)d_in[3];
  const float* m1  = (const float*)d_in[4];
  const float* v1  = (const float*)d_in[5];
  const float* W2  = (const float*)d_in[6];
  const float* g2  = (const float*)d_in[7];
  const float* b2  = (const float*)d_in[8];
  const float* m2  = (const float*)d_in[9];
  const float* v2  = (const float*)d_in[10];
  const float* W3  = (const float*)d_in[11];
  const float* g3  = (const float*)d_in[12];
  const float* b3  = (const float*)d_in[13];
  const float* m3  = (const float*)d_in[14];
  const float* v3  = (const float*)d_in[15];
  const float* W4  = (const float*)d_in[16];
  const float* g4  = (const float*)d_in[17];
  const float* b4  = (const float*)d_in[18];
  const float* m4  = (const float*)d_in[19];
  const float* v4  = (const float*)d_in[20];
  const float* W5  = (const float*)d_in[21];
  const float* g5  = (const float*)d_in[22];
  const float* b5  = (const float*)d_in[23];
  const float* m5  = (const float*)d_in[24];
  const float* v5  = (const float*)d_in[25];
  const float* L1  = (const float*)d_in[26];
  const float* gl1 = (const float*)d_in[27];
  const float* bl1 = (const float*)d_in[28];
  const float* ml1 = (const float*)d_in[29];
  const float* vl1 = (const float*)d_in[30];
  const float* L2  = (const float*)d_in[31];
  const float* L2b = (const float*)d_in[32];
  const float* gl2 = (const float*)d_in[33];
  const float* bl2 = (const float*)d_in[34];
  const float* ml2 = (const float*)d_in[35];
  const float* vl2 = (const float*)d_in[36];
  const float* L3  = (const float*)d_in[37];
  const float* L3b = (const float*)d_in[38];

  // workspace layout (float offsets). Dbuf (one batch, 64MB) aliases PQ:
  // per layer, D is dead after the scans, PQ written afterwards.
  float* ws   = (float*)d_ws;
  float* xt   = ws;                      //   262144
  float* sq   = ws + 262144;             //    32768
  int*   idx  = (int*)(ws + 294912);     //   655360 ints
  float* Dbuf = ws + 950272;             // 16777216 (= PQ region)
  float* PQ   = Dbuf;
  float* xc   = ws + 17727488;           // 16777216  (8,4096,512) concat x1..x4
  float* pmax = ws + 34504704;           //   262144
  float* psum = ws + 34766848;           //   262144
  float* pool = ws + 35028992;           //    16384
  float* oA   = ws + 35045376;           //     4096
  float* oB   = ws + 35049472;           //     2048
  if (ws_size < (size_t)35051520 * 4) return;  // ~140 MB scratch

  k_transpose_pad<<<128, 256, 0, stream>>>(x, xt);

  // ---- edge conv 1: in xt (C=6 padded to 8), out xc[:,:,0:64] ----
  k_sqnorm<<<128, 256, 0, stream>>>(xt, 8, 2, sq);
  for (int b = 0; b < NB; ++b){
    k_dgemm<<<dim3(32,32), 256, 0, stream>>>(xt + (size_t)b*NPTS*8, 8, 8, sq + b*NPTS, Dbuf);
    k_scan<<<1024, 256, 0, stream>>>(Dbuf, idx + (size_t)b*NPTS*KNN);
  }
  k_gemm_pq<<<dim3(256,2), 256, 0, stream>>>(xt, 8, 6, W1, 12, 64, PQ);
  k_gather_conv<<<8192, 256, 0, stream>>>(PQ, idx, g1, b1, m1, v1, xc, 6, 0);

  // ---- edge conv 2: in xc[:,:,0:64], out xc[:,:,64:128] ----
  k_sqnorm<<<128, 256, 0, stream>>>(xc, 512, 16, sq);
  for (int b = 0; b < NB; ++b){
    k_dgemm<<<dim3(32,32), 256, 0, stream>>>(xc + (size_t)b*NPTS*512, 512, 64, sq + b*NPTS, Dbuf);
    k_scan<<<1024, 256, 0, stream>>>(Dbuf, idx + (size_t)b*NPTS*KNN);
  }
  k_gemm_pq<<<dim3(256,2), 256, 0, stream>>>(xc, 512, 64, W2, 128, 64, PQ);
  k_gather_conv<<<8192, 256, 0, stream>>>(PQ, idx, g2, b2, m2, v2, xc, 6, 64);

  // ---- edge conv 3: in xc[:,:,64:128], out xc[:,:,128:256] ----
  k_sqnorm<<<128, 256, 0, stream>>>(xc + 64, 512, 16, sq);
  for (int b = 0; b < NB; ++b){
    k_dgemm<<<dim3(32,32), 256, 0, stream>>>(xc + 64 + (size_t)b*NPTS*512, 512, 64, sq + b*NPTS, Dbuf);
    k_scan<<<1024, 256, 0, stream>>>(Dbuf, idx + (size_t)b*NPTS*KNN);
  }
  k_gemm_pq<<<dim3(256,4), 256, 0, stream>>>(xc + 64, 512, 64, W3, 128, 128, PQ);
  k_gather_conv<<<16384, 256, 0, stream>>>(PQ, idx, g3, b3, m3, v3, xc, 7, 128);

  // ---- edge conv 4: in xc[:,:,128:256], out xc[:,:,256:512] ----
  k_sqnorm<<<128, 256, 0, stream>>>(xc + 128, 512, 32, sq);
  for (int b = 0; b < NB; ++b){
    k_dgemm<<<dim3(32,32), 256, 0, stream>>>(xc + 128 + (size_t)b*NPTS*512, 512, 128, sq + b*NPTS, Dbuf);
    k_scan<<<1024, 256, 0, stream>>>(Dbuf, idx + (size_t)b*NPTS*KNN);
  }
  k_gemm_pq<<<dim3(256,8), 256, 0, stream>>>(xc + 128, 512, 128, W4, 256, 256, PQ);
  k_gather_conv<<<32768, 256, 0, stream>>>(PQ, idx, g4, b4, m4, v4, xc, 8, 256);

  // ---- global feature: h = lrelu(bn(xc @ W5^T)), max+mean pool over N ----
  k_gemm_w5_pool<<<dim3(256,8), 256, 0, stream>>>(xc, W5, g5, b5, m5, v5, pmax, psum);
  k_pool_reduce<<<32, 256, 0, stream>>>(pmax, psum, pool);

  // ---- classifier head ----
  k_fc1<<<16, 256, 0, stream>>>(pool, L1, gl1, bl1, ml1, vl1, oA);
  k_fc2<<<8, 256, 0, stream>>>(oA, L2, L2b, gl2, bl2, ml2, vl2, oB);
  k_fc3<<<1, 64, 0, stream>>>(oB, L3, L3b, (float*)d_out);
}

// Round 11
// 3501.203 us; speedup vs baseline: 2.0680x; 1.0570x over previous
//
#include <hip/hip_runtime.h>

// DGCNN forward, fp32 throughout.
// R11: R10 structure (proven) + staging fix in all three GEMM kernels:
// float4 global loads (64B/4-lane coalesced) + transposed scalar LDS stores
// whose per-instruction bank pattern is 2-way (free). Kills the 8-way
// staging-store conflicts (w5_pool SQ_LDS_BANK_CONFLICT 8.4M) present in
// k_dgemm / k_gemm_pq / k_gemm_w5_pool. Scan & everything else unchanged.

#define NPTS   4096
#define NB     8
#define BNR    32768      // NB*NPTS
#define KNN    20
#define EPSBN  1e-5f

__device__ __forceinline__ float lrelu(float x){ return x > 0.f ? x : 0.2f*x; }

// x (8,6,4096) -> xt (8,4096,8), channels 6,7 zero-padded
__global__ __launch_bounds__(256) void k_transpose_pad(const float* __restrict__ x,
                                                       float* __restrict__ xt){
  int id = blockIdx.x*256 + threadIdx.x;          // 0..32767
  int b = id >> 12, n = id & (NPTS-1);
  const float* xb = x + (size_t)b*6*NPTS + n;
  float* o = xt + (size_t)id*8;
#pragma unroll
  for (int c = 0; c < 6; ++c) o[c] = xb[(size_t)c*NPTS];
  o[6] = 0.f; o[7] = 0.f;
}

// squared norm per row (c4 float4 groups, row stride xstride floats)
__global__ __launch_bounds__(256) void k_sqnorm(const float* __restrict__ X, int xstride, int c4,
                                                float* __restrict__ sq){
  int id = blockIdx.x*256 + threadIdx.x;
  const float4* r = (const float4*)(X + (size_t)id*xstride);
  float s = 0.f;
  for (int c = 0; c < c4; ++c){ float4 v = r[c]; s += v.x*v.x + v.y*v.y + v.z*v.z + v.w*v.w; }
  sq[id] = s;
}

// D[i][j] = 2*dot(x_i,x_j) - sq_i - sq_j for one batch. 128x128 tile, 8x8 micro,
// conflict-free compute reads (split col groups) AND conflict-free staging
// (float4 load, transposed store: per-instruction 2-way).
__global__ __launch_bounds__(256) void k_dgemm(const float* __restrict__ X, int xstride, int Kdim,
                                               const float* __restrict__ sqv,
                                               float* __restrict__ D){
  __shared__ float As[16][132];
  __shared__ float Bs[16][132];
  const int i0 = blockIdx.y*128, j0 = blockIdx.x*128;
  const int tid = threadIdx.x, tx = tid & 15, ty = tid >> 4;
  const int srow = tid >> 2;           // 0..63 (+64 on 2nd iter)
  const int skc  = (tid & 3) << 2;     // 0,4,8,12
  float acc[8][8] = {};
  for (int k0 = 0; k0 < Kdim; k0 += 16){
    bool ok = (k0 + skc) < Kdim;       // Kdim is a multiple of 4
#pragma unroll
    for (int i = 0; i < 2; ++i){
      int row = srow + 64*i;
      float4 va = make_float4(0.f,0.f,0.f,0.f), vb = va;
      if (ok){
        va = *(const float4*)&X[(size_t)(i0+row)*xstride + k0+skc];
        vb = *(const float4*)&X[(size_t)(j0+row)*xstride + k0+skc];
      }
      As[skc+0][row]=va.x; As[skc+1][row]=va.y; As[skc+2][row]=va.z; As[skc+3][row]=va.w;
      Bs[skc+0][row]=vb.x; Bs[skc+1][row]=vb.y; Bs[skc+2][row]=vb.z; Bs[skc+3][row]=vb.w;
    }
    __syncthreads();
#pragma unroll
    for (int kk = 0; kk < 16; ++kk){
      float a[8], b[8];
      *(float4*)&a[0] = *(const float4*)&As[kk][ty*8];
      *(float4*)&a[4] = *(const float4*)&As[kk][ty*8+4];
      *(float4*)&b[0] = *(const float4*)&Bs[kk][tx*4];
      *(float4*)&b[4] = *(const float4*)&Bs[kk][64 + tx*4];
#pragma unroll
      for (int r = 0; r < 8; ++r)
#pragma unroll
        for (int c = 0; c < 8; ++c)
          acc[r][c] = fmaf(a[r], b[c], acc[r][c]);
    }
    __syncthreads();
  }
  float si[8], sj[8];
#pragma unroll
  for (int r = 0; r < 8; ++r) si[r] = sqv[i0 + ty*8 + r];
#pragma unroll
  for (int c = 0; c < 4; ++c){
    sj[c]   = sqv[j0 + tx*4 + c];
    sj[c+4] = sqv[j0 + 64 + tx*4 + c];
  }
#pragma unroll
  for (int r = 0; r < 8; ++r){
    float* drow = D + (size_t)(i0 + ty*8 + r)*NPTS;
    *(float4*)&drow[j0 + tx*4] =
      make_float4(2.f*acc[r][0]-si[r]-sj[0], 2.f*acc[r][1]-si[r]-sj[1],
                  2.f*acc[r][2]-si[r]-sj[2], 2.f*acc[r][3]-si[r]-sj[3]);
    *(float4*)&drow[j0 + 64 + tx*4] =
      make_float4(2.f*acc[r][4]-si[r]-sj[4], 2.f*acc[r][5]-si[r]-sj[5],
                  2.f*acc[r][6]-si[r]-sj[6], 2.f*acc[r][7]-si[r]-sj[7]);
  }
}

// one wave per row: top-20 (value desc, tie -> lower index) in lanes 0..19.
// float4 loads: 256 cols per ballot round, 16 rounds per row. (R2/R10-proven.)
__global__ __launch_bounds__(256) void k_scan(const float* __restrict__ D,
                                              int* __restrict__ idx){
  const int lane = threadIdx.x & 63;
  const int wv   = threadIdx.x >> 6;
  const int row  = blockIdx.x*4 + wv;             // 0..4095 within batch
  const float4* drow = (const float4*)(D + (size_t)row*NPTS);
  float lv = -3e38f; int li = 0;
  float thr = -3e38f;
  float4 cur = drow[lane];
  for (int m0 = 0; m0 < NPTS; m0 += 256){
    float4 nxt = make_float4(-3e38f,-3e38f,-3e38f,-3e38f);
    if (m0 + 256 < NPTS) nxt = drow[((m0+256) >> 2) + lane];
    float mx4 = fmaxf(fmaxf(cur.x, cur.y), fmaxf(cur.z, cur.w));
    unsigned long long mask = __ballot(mx4 > thr);
    while (mask){
      int l = __ffsll(mask) - 1;
      mask &= mask - 1;
      float v0 = __shfl(cur.x, l);
      float v1 = __shfl(cur.y, l);
      float v2 = __shfl(cur.z, l);
      float v3 = __shfl(cur.w, l);
      int c0 = m0 + 4*l;
#pragma unroll
      for (int j = 0; j < 4; ++j){
        float dv = (j==0) ? v0 : (j==1) ? v1 : (j==2) ? v2 : v3;
        if (dv > thr){
          float upv = __shfl_up(lv, 1);
          int   upi = __shfl_up(li, 1);
          if (lane < KNN){
            bool ins  = dv > lv;                  // list sorted desc
            bool insp = (lane > 0) && (dv > upv);
            if (ins){ lv = insp ? upv : dv; li = insp ? upi : (c0 + j); }
          }
          thr = __shfl(lv, KNN-1);
        }
      }
    }
    cur = nxt;
  }
  if (lane < KNN) idx[(size_t)row*KNN + lane] = li;
}

// PQ(M x 2*Och) = X(M x Kdim) @ [Wa; Wb]^T where Wa=W[:, :Kdim], Wb=W[:, Kdim:2Kdim].
// BM=128, BO=64, BK=16, 8x4 micro. Xs staging vectorized+transposed (layer-1
// Kdim=6 exact: xt pad cols are 0, masked W rows are 0).
__global__ __launch_bounds__(256) void k_gemm_pq(const float* __restrict__ X, int xstride, int Kdim,
                                                 const float* __restrict__ W, int wstride, int Och,
                                                 float* __restrict__ PQ){
  __shared__ float Xs[16][132];
  __shared__ float Ws[16][68];
  const int m0 = blockIdx.x*128, o0 = blockIdx.y*64;
  const int tid = threadIdx.x, tx = tid & 15, ty = tid >> 4;
  const int srow = tid >> 2;
  const int skc  = (tid & 3) << 2;
  const int O2 = 2*Och;
  float acc[8][4] = {};
  for (int k0 = 0; k0 < Kdim; k0 += 16){
    bool ok = (k0 + skc) < Kdim;
#pragma unroll
    for (int i = 0; i < 2; ++i){
      int row = srow + 64*i;
      float4 vx = make_float4(0.f,0.f,0.f,0.f);
      if (ok) vx = *(const float4*)&X[(size_t)(m0+row)*xstride + k0+skc];
      Xs[skc+0][row]=vx.x; Xs[skc+1][row]=vx.y; Xs[skc+2][row]=vx.z; Xs[skc+3][row]=vx.w;
    }
#pragma unroll
    for (int i = 0; i < 4; ++i){
      int li = tid + 256*i;
      int row = li >> 4, kk = li & 15;
      int orow = o0 + row;
      const float* wr = (orow < Och) ? (W + (size_t)orow*wstride)
                                     : (W + (size_t)(orow-Och)*wstride + Kdim);
      bool okw = (k0 + kk) < Kdim;
      Ws[kk][row] = okw ? wr[k0+kk] : 0.f;
    }
    __syncthreads();
#pragma unroll
    for (int kk = 0; kk < 16; ++kk){
      float xa[8], wb[4];
      *(float4*)&xa[0] = *(const float4*)&Xs[kk][ty*8];
      *(float4*)&xa[4] = *(const float4*)&Xs[kk][ty*8+4];
      *(float4*)wb     = *(const float4*)&Ws[kk][tx*4];
#pragma unroll
      for (int i = 0; i < 8; ++i)
#pragma unroll
        for (int j = 0; j < 4; ++j)
          acc[i][j] = fmaf(xa[i], wb[j], acc[i][j]);
    }
    __syncthreads();
  }
#pragma unroll
  for (int i = 0; i < 8; ++i){
    float4 v = make_float4(acc[i][0], acc[i][1], acc[i][2], acc[i][3]);
    *(float4*)&PQ[(size_t)(m0+ty*8+i)*O2 + o0 + tx*4] = v;
  }
}

// out[n,o] = lrelu(scale*(red_k P[mk,o] - P[n,o] + Q[n,o]) + beta); red=max if scale>=0 else min
// P(m,o) = PQ[m*2O + o]; Q(n,o) = PQ[n*2O + O + o]
__global__ __launch_bounds__(256) void k_gather_conv(const float* __restrict__ PQ,
                                                     const int* __restrict__ idx,
                                                     const float* __restrict__ g,
                                                     const float* __restrict__ bb,
                                                     const float* __restrict__ rm,
                                                     const float* __restrict__ rv,
                                                     float* __restrict__ Out, int oshift, int choff){
  const int O = 1 << oshift;
  int id = blockIdx.x*256 + threadIdx.x;
  int gn = id >> oshift;
  int o  = id & (O-1);
  int bbase = (gn >> 12) * NPTS;
  const int* ip = idx + (size_t)gn*KNN;
  float vmax = -3e38f, vmin = 3e38f;
#pragma unroll
  for (int k = 0; k < KNN; ++k){
    int m = ip[k];
    float v = PQ[((size_t)(bbase + m) << (oshift+1)) + o];
    vmax = fmaxf(vmax, v);
    vmin = fminf(vmin, v);
  }
  float scale = g[o] * rsqrtf(rv[o] + EPSBN);
  float beta  = bb[o] - rm[o]*scale;
  float R = (scale >= 0.f) ? vmax : vmin;
  size_t self = (size_t)gn << (oshift+1);
  float h = R - PQ[self + o] + PQ[self + O + o];
  Out[(size_t)gn*512 + choff + o] = lrelu(fmaf(scale, h, beta));
}

// h = lrelu(bn(xc @ W5^T)) tile (128x128, 8x8 micro, split col groups),
// fused partial max/sum over rows. Vectorized+transposed staging.
__global__ __launch_bounds__(256) void k_gemm_w5_pool(const float* __restrict__ X,
                                                      const float* __restrict__ W,
                                                      const float* __restrict__ g,
                                                      const float* __restrict__ bb,
                                                      const float* __restrict__ rm,
                                                      const float* __restrict__ rv,
                                                      float* __restrict__ pmax,
                                                      float* __restrict__ psum){
  __shared__ float Xs[16][132];
  __shared__ float Ws[16][132];
  __shared__ float red[2][16][128];
  const int m0 = blockIdx.x*128, o0 = blockIdx.y*128;
  const int tid = threadIdx.x, tx = tid & 15, ty = tid >> 4;
  const int srow = tid >> 2;
  const int skc  = (tid & 3) << 2;
  float acc[8][8] = {};
  for (int k0 = 0; k0 < 512; k0 += 16){
#pragma unroll
    for (int i = 0; i < 2; ++i){
      int row = srow + 64*i;
      float4 vx = *(const float4*)&X[(size_t)(m0+row)*512 + k0+skc];
      float4 vw = *(const float4*)&W[(size_t)(o0+row)*512 + k0+skc];
      Xs[skc+0][row]=vx.x; Xs[skc+1][row]=vx.y; Xs[skc+2][row]=vx.z; Xs[skc+3][row]=vx.w;
      Ws[skc+0][row]=vw.x; Ws[skc+1][row]=vw.y; Ws[skc+2][row]=vw.z; Ws[skc+3][row]=vw.w;
    }
    __syncthreads();
#pragma unroll
    for (int kk = 0; kk < 16; ++kk){
      float xa[8], wb[8];
      *(float4*)&xa[0] = *(const float4*)&Xs[kk][ty*8];
      *(float4*)&xa[4] = *(const float4*)&Xs[kk][ty*8+4];
      *(float4*)&wb[0] = *(const float4*)&Ws[kk][tx*4];
      *(float4*)&wb[4] = *(const float4*)&Ws[kk][64 + tx*4];
#pragma unroll
      for (int i = 0; i < 8; ++i)
#pragma unroll
        for (int j = 0; j < 8; ++j)
          acc[i][j] = fmaf(xa[i], wb[j], acc[i][j]);
    }
    __syncthreads();
  }
#pragma unroll
  for (int j = 0; j < 8; ++j){
    int ocol = (j < 4) ? (tx*4 + j) : (64 + tx*4 + j - 4);
    int o = o0 + ocol;
    float scale = g[o] * rsqrtf(rv[o] + EPSBN);
    float beta  = bb[o] - rm[o]*scale;
    float mx = -3e38f, sm = 0.f;
#pragma unroll
    for (int i = 0; i < 8; ++i){
      float h = lrelu(fmaf(scale, acc[i][j], beta));
      mx = fmaxf(mx, h);
      sm += h;
    }
    red[0][ty][ocol] = mx;
    red[1][ty][ocol] = sm;
  }
  __syncthreads();
  if (tid < 128){
    float mx = -3e38f, sm = 0.f;
#pragma unroll
    for (int t = 0; t < 16; ++t){
      mx = fmaxf(mx, red[0][t][tid]);
      sm += red[1][t][tid];
    }
    pmax[(size_t)blockIdx.x*1024 + o0 + tid] = mx;
    psum[(size_t)blockIdx.x*1024 + o0 + tid] = sm;
  }
}

__global__ __launch_bounds__(256) void k_pool_reduce(const float* __restrict__ pmax,
                                                     const float* __restrict__ psum,
                                                     float* __restrict__ pooled){
  int id = blockIdx.x*256 + threadIdx.x;   // 8192
  int b = id >> 10, o = id & 1023;
  float mx = -3e38f, sm = 0.f;
  for (int t = 0; t < 32; ++t){
    mx = fmaxf(mx, pmax[(size_t)(b*32+t)*1024 + o]);
    sm += psum[(size_t)(b*32+t)*1024 + o];
  }
  pooled[(size_t)b*2048 + o] = mx;
  pooled[(size_t)b*2048 + 1024 + o] = sm * (1.f/NPTS);
}

__global__ __launch_bounds__(256) void k_fc1(const float* __restrict__ pooled,
                                             const float* __restrict__ W,
                                             const float* __restrict__ g,
                                             const float* __restrict__ bb,
                                             const float* __restrict__ rm,
                                             const float* __restrict__ rv,
                                             float* __restrict__ out){
  __shared__ float4 xs[512];
  int b = blockIdx.x >> 1;
  int o = ((blockIdx.x & 1) << 8) + threadIdx.x;
  const float4* pr = (const float4*)(pooled + (size_t)b*2048);
  for (int l = threadIdx.x; l < 512; l += 256) xs[l] = pr[l];
  __syncthreads();
  const float4* wr = (const float4*)(W + (size_t)o*2048);
  float s0=0.f, s1=0.f, s2=0.f, s3=0.f;
#pragma unroll 4
  for (int c = 0; c < 512; ++c){
    float4 w = wr[c], v = xs[c];
    s0 = fmaf(v.x, w.x, s0); s1 = fmaf(v.y, w.y, s1);
    s2 = fmaf(v.z, w.z, s2); s3 = fmaf(v.w, w.w, s3);
  }
  float h = (s0+s1)+(s2+s3);
  float scale = g[o] * rsqrtf(rv[o] + EPSBN);
  float beta  = bb[o] - rm[o]*scale;
  out[(size_t)b*512 + o] = lrelu(fmaf(scale, h, beta));
}

__global__ __launch_bounds__(256) void k_fc2(const float* __restrict__ in,
                                             const float* __restrict__ W,
                                             const float* __restrict__ bias,
                                             const float* __restrict__ g,
                                             const float* __restrict__ bb,
                                             const float* __restrict__ rm,
                                             const float* __restrict__ rv,
                                             float* __restrict__ out){
  __shared__ float4 xs[128];
  int b = blockIdx.x;
  int o = threadIdx.x;
  const float4* pr = (const float4*)(in + (size_t)b*512);
  if (threadIdx.x < 128) xs[threadIdx.x] = pr[threadIdx.x];
  __syncthreads();
  const float4* wr = (const float4*)(W + (size_t)o*512);
  float s0=0.f, s1=0.f, s2=0.f, s3=0.f;
#pragma unroll 4
  for (int c = 0; c < 128; ++c){
    float4 w = wr[c], v = xs[c];
    s0 = fmaf(v.x, w.x, s0); s1 = fmaf(v.y, w.y, s1);
    s2 = fmaf(v.z, w.z, s2); s3 = fmaf(v.w, w.w, s3);
  }
  float h = (s0+s1)+(s2+s3) + bias[o];
  float scale = g[o] * rsqrtf(rv[o] + EPSBN);
  float beta  = bb[o] - rm[o]*scale;
  out[(size_t)b*256 + o] = lrelu(fmaf(scale, h, beta));
}

__global__ __launch_bounds__(64) void k_fc3(const float* __restrict__ in,
                                            const float* __restrict__ W,
                                            const float* __restrict__ bias,
                                            float* __restrict__ out){
  int t = threadIdx.x;
  if (t >= 16) return;
  int b = t >> 1, o = t & 1;
  const float* xr = in + (size_t)b*256;
  const float* wr = W + (size_t)o*256;
  float s = 0.f;
  for (int c = 0; c < 256; ++c) s = fmaf(xr[c], wr[c], s);
  out[b*2 + o] = s + bias[o];
}

extern "C" void kernel_launch(void* const* d_in, const int* in_sizes, int n_in,
                              void* d_out, int out_size, void* d_ws, size_t ws_size,
                              hipStream_t stream){
  (void)in_sizes; (void)n_in; (void)out_size;
  const float* x   = (const float*)d_in[0];
  const float* W1  = (const float*)d_in[1];
  const float* g1  = (const float*)d_in[2];
  const float* b1  = (const float*)d_in[3];
  const float* m1  = (const float*)d_in[4];
  const float* v1  = (const float*)d_in[5];
  const float* W2  = (const float*)d_in[6];
  const float* g2  = (const float*)d_in[7];
  const float* b2  = (const float*)d_in[8];
  const float* m2  = (const float*)d_in[9];
  const float* v2  = (const float*)d_in[10];
  const float* W3  = (const float*)d_in[11];
  const float* g3  = (const float*)d_in[12];
  const float* b3  = (const float*)d_in[13];
  const float* m3  = (const float*)d_in[14];
  const float* v3  = (const float*)d_in[15];
  const float* W4  = (const float*)d_in[16];
  const float* g4  = (const float*)d_in[17];
  const float* b4  = (const float*)d_in[18];
  const float* m4  = (const float*)d_in[19];
  const float* v4  = (const float*)d_in[20];
  const float* W5  = (const float*)d_in[21];
  const float* g5  = (const float*)d_in[22];
  const float* b5  = (const float*)d_in[23];
  const float* m5  = (const float*)d_in[24];
  const float* v5  = (const float*)d_in[25];
  const float* L1  = (const float*)d_in[26];
  const float* gl1 = (const float*)d_in[27];
  const float* bl1 = (const float*)d_in[28];
  const float* ml1 = (const float*)d_in[29];
  const float* vl1 = (const float*)d_in[30];
  const float* L2  = (const float*)d_in[31];
  const float* L2b = (const float*)d_in[32];
  const float* gl2 = (const float*)d_in[33];
  const float* bl2 = (const float*)d_in[34];
  const float* ml2 = (const float*)d_in[35];
  const float* vl2 = (const float*)d_in[36];
  const float* L3  = (const float*)d_in[37];
  const float* L3b = (const float*)d_in[38];

  // workspace layout (float offsets). Dbuf (one batch, 64MB) aliases PQ:
  // per layer, D is dead after the scans, PQ written afterwards.
  float* ws   = (float*)d_ws;
  float* xt   = ws;                      //   262144
  float* sq   = ws + 262144;             //    32768
  int*   idx  = (int*)(ws + 294912);     //   655360 ints
  float* Dbuf = ws + 950272;             // 16777216 (= PQ region)
  float* PQ   = Dbuf;
  float* xc   = ws + 17727488;           // 16777216  (8,4096,512) concat x1..x4
  float* pmax = ws + 34504704;           //   262144
  float* psum = ws + 34766848;           //   262144
  float* pool = ws + 35028992;           //    16384
  float* oA   = ws + 35045376;           //     4096
  float* oB   = ws + 35049472;           //     2048
  if (ws_size < (size_t)35051520 * 4) return;  // ~140 MB scratch

  k_transpose_pad<<<128, 256, 0, stream>>>(x, xt);

  // ---- edge conv 1: in xt (C=6 padded to 8), out xc[:,:,0:64] ----
  k_sqnorm<<<128, 256, 0, stream>>>(xt, 8, 2, sq);
  for (int b = 0; b < NB; ++b){
    k_dgemm<<<dim3(32,32), 256, 0, stream>>>(xt + (size_t)b*NPTS*8, 8, 8, sq + b*NPTS, Dbuf);
    k_scan<<<1024, 256, 0, stream>>>(Dbuf, idx + (size_t)b*NPTS*KNN);
  }
  k_gemm_pq<<<dim3(256,2), 256, 0, stream>>>(xt, 8, 6, W1, 12, 64, PQ);
  k_gather_conv<<<8192, 256, 0, stream>>>(PQ, idx, g1, b1, m1, v1, xc, 6, 0);

  // ---- edge conv 2: in xc[:,:,0:64], out xc[:,:,64:128] ----
  k_sqnorm<<<128, 256, 0, stream>>>(xc, 512, 16, sq);
  for (int b = 0; b < NB; ++b){
    k_dgemm<<<dim3(32,32), 256, 0, stream>>>(xc + (size_t)b*NPTS*512, 512, 64, sq + b*NPTS, Dbuf);
    k_scan<<<1024, 256, 0, stream>>>(Dbuf, idx + (size_t)b*NPTS*KNN);
  }
  k_gemm_pq<<<dim3(256,2), 256, 0, stream>>>(xc, 512, 64, W2, 128, 64, PQ);
  k_gather_conv<<<8192, 256, 0, stream>>>(PQ, idx, g2, b2, m2, v2, xc, 6, 64);

  // ---- edge conv 3: in xc[:,:,64:128], out xc[:,:,128:256] ----
  k_sqnorm<<<128, 256, 0, stream>>>(xc + 64, 512, 16, sq);
  for (int b = 0; b < NB; ++b){
    k_dgemm<<<dim3(32,32), 256, 0, stream>>>(xc + 64 + (size_t)b*NPTS*512, 512, 64, sq + b*NPTS, Dbuf);
    k_scan<<<1024, 256, 0, stream>>>(Dbuf, idx + (size_t)b*NPTS*KNN);
  }
  k_gemm_pq<<<dim3(256,4), 256, 0, stream>>>(xc + 64, 512, 64, W3, 128, 128, PQ);
  k_gather_conv<<<16384, 256, 0, stream>>>(PQ, idx, g3, b3, m3, v3, xc, 7, 128);

  // ---- edge conv 4: in xc[:,:,128:256], out xc[:,:,256:512] ----
  k_sqnorm<<<128, 256, 0, stream>>>(xc + 128, 512, 32, sq);
  for (int b = 0; b < NB; ++b){
    k_dgemm<<<dim3(32,32), 256, 0, stream>>>(xc + 128 + (size_t)b*NPTS*512, 512, 128, sq + b*NPTS, Dbuf);
    k_scan<<<1024, 256, 0, stream>>>(Dbuf, idx + (size_t)b*NPTS*KNN);
  }
  k_gemm_pq<<<dim3(256,8), 256, 0, stream>>>(xc + 128, 512, 128, W4, 256, 256, PQ);
  k_gather_conv<<<32768, 256, 0, stream>>>(PQ, idx, g4, b4, m4, v4, xc, 8, 256);

  // ---- global feature: h = lrelu(bn(xc @ W5^T)), max+mean pool over N ----
  k_gemm_w5_pool<<<dim3(256,8), 256, 0, stream>>>(xc, W5, g5, b5, m5, v5, pmax, psum);
  k_pool_reduce<<<32, 256, 0, stream>>>(pmax, psum, pool);

  // ---- classifier head ----
  k_fc1<<<16, 256, 0, stream>>>(pool, L1, gl1, bl1, ml1, vl1, oA);
  k_fc2<<<8, 256, 0, stream>>>(oA, L2, L2b, gl2, bl2, ml2, vl2, oB);
  k_fc3<<<1, 64, 0, stream>>>(oB, L3, L3b, (float*)d_out);
}

// Round 12
// 3458.976 us; speedup vs baseline: 2.0932x; 1.0122x over previous
//
#include <hip/hip_runtime.h>

// DGCNN forward, fp32 throughout.
// R12: barrier-halving. k_gemm_w5_pool and k_dgemm move to BK=32 k-steps
// (2 barriers per 32-K instead of per 16-K); w5's red[] buffer is unioned
// onto the staging LDS (used only after final compute sync) so LDS stays
// ~33.8KB -> 4 blocks/CU. k_dgemm templated: BK=8 for layer-1 (K=8, halves
// its kk work vs R11), BK=32 for K=64/128. Staging keeps R11's conflict-free
// float4-load + transposed-store mapping. FMA order unchanged (bitwise-same
// distances -> same neighbor sets). pq/scan/gather/fc unchanged.

#define NPTS   4096
#define NB     8
#define BNR    32768      // NB*NPTS
#define KNN    20
#define EPSBN  1e-5f

__device__ __forceinline__ float lrelu(float x){ return x > 0.f ? x : 0.2f*x; }

// x (8,6,4096) -> xt (8,4096,8), channels 6,7 zero-padded
__global__ __launch_bounds__(256) void k_transpose_pad(const float* __restrict__ x,
                                                       float* __restrict__ xt){
  int id = blockIdx.x*256 + threadIdx.x;          // 0..32767
  int b = id >> 12, n = id & (NPTS-1);
  const float* xb = x + (size_t)b*6*NPTS + n;
  float* o = xt + (size_t)id*8;
#pragma unroll
  for (int c = 0; c < 6; ++c) o[c] = xb[(size_t)c*NPTS];
  o[6] = 0.f; o[7] = 0.f;
}

// squared norm per row (c4 float4 groups, row stride xstride floats)
__global__ __launch_bounds__(256) void k_sqnorm(const float* __restrict__ X, int xstride, int c4,
                                                float* __restrict__ sq){
  int id = blockIdx.x*256 + threadIdx.x;
  const float4* r = (const float4*)(X + (size_t)id*xstride);
  float s = 0.f;
  for (int c = 0; c < c4; ++c){ float4 v = r[c]; s += v.x*v.x + v.y*v.y + v.z*v.z + v.w*v.w; }
  sq[id] = s;
}

// D[i][j] = 2*dot(x_i,x_j) - sq_i - sq_j for one batch. 128x128 tile, 8x8 micro.
// BK-templated k-step (8 for K=8, 32 for K=64/128); conflict-free staging.
template<int BK>
__global__ __launch_bounds__(256) void k_dgemm(const float* __restrict__ X, int xstride, int Kdim,
                                               const float* __restrict__ sqv,
                                               float* __restrict__ D){
  __shared__ float As[BK][132];
  __shared__ float Bs[BK][132];
  const int i0 = blockIdx.y*128, j0 = blockIdx.x*128;
  const int tid = threadIdx.x, tx = tid & 15, ty = tid >> 4;
  float acc[8][8] = {};
  for (int k0 = 0; k0 < Kdim; k0 += BK){
    if constexpr (BK == 32){
      const int srow = tid >> 2, skc = (tid & 3) << 2;
#pragma unroll
      for (int j = 0; j < 2; ++j){
        int kc = 16*j + skc;
        bool ok = (k0 + kc) < Kdim;
#pragma unroll
        for (int i = 0; i < 2; ++i){
          int row = srow + 64*i;
          float4 va = make_float4(0.f,0.f,0.f,0.f), vb = va;
          if (ok){
            va = *(const float4*)&X[(size_t)(i0+row)*xstride + k0+kc];
            vb = *(const float4*)&X[(size_t)(j0+row)*xstride + k0+kc];
          }
          As[kc+0][row]=va.x; As[kc+1][row]=va.y; As[kc+2][row]=va.z; As[kc+3][row]=va.w;
          Bs[kc+0][row]=vb.x; Bs[kc+1][row]=vb.y; Bs[kc+2][row]=vb.z; Bs[kc+3][row]=vb.w;
        }
      }
    } else {  // BK == 8: one float4 per thread per matrix
      const int row = tid >> 1, kc = (tid & 1) << 2;
      float4 va = *(const float4*)&X[(size_t)(i0+row)*xstride + k0+kc];
      float4 vb = *(const float4*)&X[(size_t)(j0+row)*xstride + k0+kc];
      As[kc+0][row]=va.x; As[kc+1][row]=va.y; As[kc+2][row]=va.z; As[kc+3][row]=va.w;
      Bs[kc+0][row]=vb.x; Bs[kc+1][row]=vb.y; Bs[kc+2][row]=vb.z; Bs[kc+3][row]=vb.w;
    }
    __syncthreads();
    constexpr int KIN = (BK < 16) ? BK : 16;
#pragma unroll
    for (int kh = 0; kh < BK/KIN; ++kh){
#pragma unroll
      for (int k2 = 0; k2 < KIN; ++k2){
        const int kk = kh*KIN + k2;
        float a[8], b[8];
        *(float4*)&a[0] = *(const float4*)&As[kk][ty*8];
        *(float4*)&a[4] = *(const float4*)&As[kk][ty*8+4];
        *(float4*)&b[0] = *(const float4*)&Bs[kk][tx*4];
        *(float4*)&b[4] = *(const float4*)&Bs[kk][64 + tx*4];
#pragma unroll
        for (int r = 0; r < 8; ++r)
#pragma unroll
          for (int c = 0; c < 8; ++c)
            acc[r][c] = fmaf(a[r], b[c], acc[r][c]);
      }
    }
    __syncthreads();
  }
  float si[8], sj[8];
#pragma unroll
  for (int r = 0; r < 8; ++r) si[r] = sqv[i0 + ty*8 + r];
#pragma unroll
  for (int c = 0; c < 4; ++c){
    sj[c]   = sqv[j0 + tx*4 + c];
    sj[c+4] = sqv[j0 + 64 + tx*4 + c];
  }
#pragma unroll
  for (int r = 0; r < 8; ++r){
    float* drow = D + (size_t)(i0 + ty*8 + r)*NPTS;
    *(float4*)&drow[j0 + tx*4] =
      make_float4(2.f*acc[r][0]-si[r]-sj[0], 2.f*acc[r][1]-si[r]-sj[1],
                  2.f*acc[r][2]-si[r]-sj[2], 2.f*acc[r][3]-si[r]-sj[3]);
    *(float4*)&drow[j0 + 64 + tx*4] =
      make_float4(2.f*acc[r][4]-si[r]-sj[4], 2.f*acc[r][5]-si[r]-sj[5],
                  2.f*acc[r][6]-si[r]-sj[6], 2.f*acc[r][7]-si[r]-sj[7]);
  }
}

// one wave per row: top-20 (value desc, tie -> lower index) in lanes 0..19.
// float4 loads: 256 cols per ballot round, 16 rounds per row. (R2/R10-proven.)
__global__ __launch_bounds__(256) void k_scan(const float* __restrict__ D,
                                              int* __restrict__ idx){
  const int lane = threadIdx.x & 63;
  const int wv   = threadIdx.x >> 6;
  const int row  = blockIdx.x*4 + wv;             // 0..4095 within batch
  const float4* drow = (const float4*)(D + (size_t)row*NPTS);
  float lv = -3e38f; int li = 0;
  float thr = -3e38f;
  float4 cur = drow[lane];
  for (int m0 = 0; m0 < NPTS; m0 += 256){
    float4 nxt = make_float4(-3e38f,-3e38f,-3e38f,-3e38f);
    if (m0 + 256 < NPTS) nxt = drow[((m0+256) >> 2) + lane];
    float mx4 = fmaxf(fmaxf(cur.x, cur.y), fmaxf(cur.z, cur.w));
    unsigned long long mask = __ballot(mx4 > thr);
    while (mask){
      int l = __ffsll(mask) - 1;
      mask &= mask - 1;
      float v0 = __shfl(cur.x, l);
      float v1 = __shfl(cur.y, l);
      float v2 = __shfl(cur.z, l);
      float v3 = __shfl(cur.w, l);
      int c0 = m0 + 4*l;
#pragma unroll
      for (int j = 0; j < 4; ++j){
        float dv = (j==0) ? v0 : (j==1) ? v1 : (j==2) ? v2 : v3;
        if (dv > thr){
          float upv = __shfl_up(lv, 1);
          int   upi = __shfl_up(li, 1);
          if (lane < KNN){
            bool ins  = dv > lv;                  // list sorted desc
            bool insp = (lane > 0) && (dv > upv);
            if (ins){ lv = insp ? upv : dv; li = insp ? upi : (c0 + j); }
          }
          thr = __shfl(lv, KNN-1);
        }
      }
    }
    cur = nxt;
  }
  if (lane < KNN) idx[(size_t)row*KNN + lane] = li;
}

// PQ(M x 2*Och) = X(M x Kdim) @ [Wa; Wb]^T where Wa=W[:, :Kdim], Wb=W[:, Kdim:2Kdim].
// BM=128, BO=64, BK=16, 8x4 micro. (R11-proven; modest runtime, unchanged.)
__global__ __launch_bounds__(256) void k_gemm_pq(const float* __restrict__ X, int xstride, int Kdim,
                                                 const float* __restrict__ W, int wstride, int Och,
                                                 float* __restrict__ PQ){
  __shared__ float Xs[16][132];
  __shared__ float Ws[16][68];
  const int m0 = blockIdx.x*128, o0 = blockIdx.y*64;
  const int tid = threadIdx.x, tx = tid & 15, ty = tid >> 4;
  const int srow = tid >> 2;
  const int skc  = (tid & 3) << 2;
  const int O2 = 2*Och;
  float acc[8][4] = {};
  for (int k0 = 0; k0 < Kdim; k0 += 16){
    bool ok = (k0 + skc) < Kdim;
#pragma unroll
    for (int i = 0; i < 2; ++i){
      int row = srow + 64*i;
      float4 vx = make_float4(0.f,0.f,0.f,0.f);
      if (ok) vx = *(const float4*)&X[(size_t)(m0+row)*xstride + k0+skc];
      Xs[skc+0][row]=vx.x; Xs[skc+1][row]=vx.y; Xs[skc+2][row]=vx.z; Xs[skc+3][row]=vx.w;
    }
#pragma unroll
    for (int i = 0; i < 4; ++i){
      int li = tid + 256*i;
      int row = li >> 4, kk = li & 15;
      int orow = o0 + row;
      const float* wr = (orow < Och) ? (W + (size_t)orow*wstride)
                                     : (W + (size_t)(orow-Och)*wstride + Kdim);
      bool okw = (k0 + kk) < Kdim;
      Ws[kk][row] = okw ? wr[k0+kk] : 0.f;
    }
    __syncthreads();
#pragma unroll
    for (int kk = 0; kk < 16; ++kk){
      float xa[8], wb[4];
      *(float4*)&xa[0] = *(const float4*)&Xs[kk][ty*8];
      *(float4*)&xa[4] = *(const float4*)&Xs[kk][ty*8+4];
      *(float4*)wb     = *(const float4*)&Ws[kk][tx*4];
#pragma unroll
      for (int i = 0; i < 8; ++i)
#pragma unroll
        for (int j = 0; j < 4; ++j)
          acc[i][j] = fmaf(xa[i], wb[j], acc[i][j]);
    }
    __syncthreads();
  }
#pragma unroll
  for (int i = 0; i < 8; ++i){
    float4 v = make_float4(acc[i][0], acc[i][1], acc[i][2], acc[i][3]);
    *(float4*)&PQ[(size_t)(m0+ty*8+i)*O2 + o0 + tx*4] = v;
  }
}

// out[n,o] = lrelu(scale*(red_k P[mk,o] - P[n,o] + Q[n,o]) + beta); red=max if scale>=0 else min
// P(m,o) = PQ[m*2O + o]; Q(n,o) = PQ[n*2O + O + o]
__global__ __launch_bounds__(256) void k_gather_conv(const float* __restrict__ PQ,
                                                     const int* __restrict__ idx,
                                                     const float* __restrict__ g,
                                                     const float* __restrict__ bb,
                                                     const float* __restrict__ rm,
                                                     const float* __restrict__ rv,
                                                     float* __restrict__ Out, int oshift, int choff){
  const int O = 1 << oshift;
  int id = blockIdx.x*256 + threadIdx.x;
  int gn = id >> oshift;
  int o  = id & (O-1);
  int bbase = (gn >> 12) * NPTS;
  const int* ip = idx + (size_t)gn*KNN;
  float vmax = -3e38f, vmin = 3e38f;
#pragma unroll
  for (int k = 0; k < KNN; ++k){
    int m = ip[k];
    float v = PQ[((size_t)(bbase + m) << (oshift+1)) + o];
    vmax = fmaxf(vmax, v);
    vmin = fminf(vmin, v);
  }
  float scale = g[o] * rsqrtf(rv[o] + EPSBN);
  float beta  = bb[o] - rm[o]*scale;
  float R = (scale >= 0.f) ? vmax : vmin;
  size_t self = (size_t)gn << (oshift+1);
  float h = R - PQ[self + o] + PQ[self + O + o];
  Out[(size_t)gn*512 + choff + o] = lrelu(fmaf(scale, h, beta));
}

// h = lrelu(bn(xc @ W5^T)) tile (128x128, 8x8 micro), BK=32 (half the barriers),
// fused partial max/sum over rows; red[] unioned onto staging LDS.
__global__ __launch_bounds__(256) void k_gemm_w5_pool(const float* __restrict__ X,
                                                      const float* __restrict__ W,
                                                      const float* __restrict__ g,
                                                      const float* __restrict__ bb,
                                                      const float* __restrict__ rm,
                                                      const float* __restrict__ rv,
                                                      float* __restrict__ pmax,
                                                      float* __restrict__ psum){
  __shared__ __align__(16) float smem[2*32*132];      // Xs[32][132] | Ws[32][132]; red aliases
  float (*Xs)[132] = (float(*)[132])smem;
  float (*Ws)[132] = (float(*)[132])(smem + 32*132);
  float* red0 = smem;                                  // [16][128] after final sync
  float* red1 = smem + 2048;                           // [16][128]
  const int m0 = blockIdx.x*128, o0 = blockIdx.y*128;
  const int tid = threadIdx.x, tx = tid & 15, ty = tid >> 4;
  const int srow = tid >> 2;
  const int skc  = (tid & 3) << 2;
  float acc[8][8] = {};
  for (int k0 = 0; k0 < 512; k0 += 32){
#pragma unroll
    for (int j = 0; j < 2; ++j){
      int kc = 16*j + skc;
#pragma unroll
      for (int i = 0; i < 2; ++i){
        int row = srow + 64*i;
        float4 vx = *(const float4*)&X[(size_t)(m0+row)*512 + k0+kc];
        float4 vw = *(const float4*)&W[(size_t)(o0+row)*512 + k0+kc];
        Xs[kc+0][row]=vx.x; Xs[kc+1][row]=vx.y; Xs[kc+2][row]=vx.z; Xs[kc+3][row]=vx.w;
        Ws[kc+0][row]=vw.x; Ws[kc+1][row]=vw.y; Ws[kc+2][row]=vw.z; Ws[kc+3][row]=vw.w;
      }
    }
    __syncthreads();
#pragma unroll
    for (int kh = 0; kh < 2; ++kh){
#pragma unroll
      for (int k2 = 0; k2 < 16; ++k2){
        const int kk = kh*16 + k2;
        float xa[8], wb[8];
        *(float4*)&xa[0] = *(const float4*)&Xs[kk][ty*8];
        *(float4*)&xa[4] = *(const float4*)&Xs[kk][ty*8+4];
        *(float4*)&wb[0] = *(const float4*)&Ws[kk][tx*4];
        *(float4*)&wb[4] = *(const float4*)&Ws[kk][64 + tx*4];
#pragma unroll
        for (int i = 0; i < 8; ++i)
#pragma unroll
          for (int j = 0; j < 8; ++j)
            acc[i][j] = fmaf(xa[i], wb[j], acc[i][j]);
      }
    }
    __syncthreads();
  }
  // staging LDS now dead (last sync above) -> reuse as reduction buffer
#pragma unroll
  for (int j = 0; j < 8; ++j){
    int ocol = (j < 4) ? (tx*4 + j) : (64 + tx*4 + j - 4);
    int o = o0 + ocol;
    float scale = g[o] * rsqrtf(rv[o] + EPSBN);
    float beta  = bb[o] - rm[o]*scale;
    float mx = -3e38f, sm = 0.f;
#pragma unroll
    for (int i = 0; i < 8; ++i){
      float h = lrelu(fmaf(scale, acc[i][j], beta));
      mx = fmaxf(mx, h);
      sm += h;
    }
    red0[ty*128 + ocol] = mx;
    red1[ty*128 + ocol] = sm;
  }
  __syncthreads();
  if (tid < 128){
    float mx = -3e38f, sm = 0.f;
#pragma unroll
    for (int t = 0; t < 16; ++t){
      mx = fmaxf(mx, red0[t*128 + tid]);
      sm += red1[t*128 + tid];
    }
    pmax[(size_t)blockIdx.x*1024 + o0 + tid] = mx;
    psum[(size_t)blockIdx.x*1024 + o0 + tid] = sm;
  }
}

__global__ __launch_bounds__(256) void k_pool_reduce(const float* __restrict__ pmax,
                                                     const float* __restrict__ psum,
                                                     float* __restrict__ pooled){
  int id = blockIdx.x*256 + threadIdx.x;   // 8192
  int b = id >> 10, o = id & 1023;
  float mx = -3e38f, sm = 0.f;
  for (int t = 0; t < 32; ++t){
    mx = fmaxf(mx, pmax[(size_t)(b*32+t)*1024 + o]);
    sm += psum[(size_t)(b*32+t)*1024 + o];
  }
  pooled[(size_t)b*2048 + o] = mx;
  pooled[(size_t)b*2048 + 1024 + o] = sm * (1.f/NPTS);
}

__global__ __launch_bounds__(256) void k_fc1(const float* __restrict__ pooled,
                                             const float* __restrict__ W,
                                             const float* __restrict__ g,
                                             const float* __restrict__ bb,
                                             const float* __restrict__ rm,
                                             const float* __restrict__ rv,
                                             float* __restrict__ out){
  __shared__ float4 xs[512];
  int b = blockIdx.x >> 1;
  int o = ((blockIdx.x & 1) << 8) + threadIdx.x;
  const float4* pr = (const float4*)(pooled + (size_t)b*2048);
  for (int l = threadIdx.x; l < 512; l += 256) xs[l] = pr[l];
  __syncthreads();
  const float4* wr = (const float4*)(W + (size_t)o*2048);
  float s0=0.f, s1=0.f, s2=0.f, s3=0.f;
#pragma unroll 4
  for (int c = 0; c < 512; ++c){
    float4 w = wr[c], v = xs[c];
    s0 = fmaf(v.x, w.x, s0); s1 = fmaf(v.y, w.y, s1);
    s2 = fmaf(v.z, w.z, s2); s3 = fmaf(v.w, w.w, s3);
  }
  float h = (s0+s1)+(s2+s3);
  float scale = g[o] * rsqrtf(rv[o] + EPSBN);
  float beta  = bb[o] - rm[o]*scale;
  out[(size_t)b*512 + o] = lrelu(fmaf(scale, h, beta));
}

__global__ __launch_bounds__(256) void k_fc2(const float* __restrict__ in,
                                             const float* __restrict__ W,
                                             const float* __restrict__ bias,
                                             const float* __restrict__ g,
                                             const float* __restrict__ bb,
                                             const float* __restrict__ rm,
                                             const float* __restrict__ rv,
                                             float* __restrict__ out){
  __shared__ float4 xs[128];
  int b = blockIdx.x;
  int o = threadIdx.x;
  const float4* pr = (const float4*)(in + (size_t)b*512);
  if (threadIdx.x < 128) xs[threadIdx.x] = pr[threadIdx.x];
  __syncthreads();
  const float4* wr = (const float4*)(W + (size_t)o*512);
  float s0=0.f, s1=0.f, s2=0.f, s3=0.f;
#pragma unroll 4
  for (int c = 0; c < 128; ++c){
    float4 w = wr[c], v = xs[c];
    s0 = fmaf(v.x, w.x, s0); s1 = fmaf(v.y, w.y, s1);
    s2 = fmaf(v.z, w.z, s2); s3 = fmaf(v.w, w.w, s3);
  }
  float h = (s0+s1)+(s2+s3) + bias[o];
  float scale = g[o] * rsqrtf(rv[o] + EPSBN);
  float beta  = bb[o] - rm[o]*scale;
  out[(size_t)b*256 + o] = lrelu(fmaf(scale, h, beta));
}

__global__ __launch_bounds__(64) void k_fc3(const float* __restrict__ in,
                                            const float* __restrict__ W,
                                            const float* __restrict__ bias,
                                            float* __restrict__ out){
  int t = threadIdx.x;
  if (t >= 16) return;
  int b = t >> 1, o = t & 1;
  const float* xr = in + (size_t)b*256;
  const float* wr = W + (size_t)o*256;
  float s = 0.f;
  for (int c = 0; c < 256; ++c) s = fmaf(xr[c], wr[c], s);
  out[b*2 + o] = s + bias[o];
}

extern "C" void kernel_launch(void* const* d_in, const int* in_sizes, int n_in,
                              void* d_out, int out_size, void* d_ws, size_t ws_size,
                              hipStream_t stream){
  (void)in_sizes; (void)n_in; (void)out_size;
  const float* x   = (const float*)d_in[0];
  const float* W1  = (const float*)d_in[1];
  const float* g1  = (const float*)d_in[2];
  const float* b1  = (const float*)d_in[3];
  const float* m1  = (const float*)d_in[4];
  const float* v1  = (const float*)d_in[5];
  const float* W2  = (const float*)d_in[6];
  const float* g2  = (const float*)d_in[7];
  const float* b2  = (const float*)d_in[8];
  const float* m2  = (const float*)d_in[9];
  const float* v2  = (const float*)d_in[10];
  const float* W3  = (const float*)d_in[11];
  const float* g3  = (const float*)d_in[12];
  const float* b3  = (const float*)d_in[13];
  const float* m3  = (const float*)d_in[14];
  const float* v3  = (const float*)d_in[15];
  const float* W4  = (const float*)d_in[16];
  const float* g4  = (const float*)d_in[17];
  const float* b4  = (const float*)d_in[18];
  const float* m4  = (const float*)d_in[19];
  const float* v4  = (const float*)d_in[20];
  const float* W5  = (const float*)d_in[21];
  const float* g5  = (const float*)d_in[22];
  const float* b5  = (const float*)d_in[23];
  const float* m5  = (const float*)d_in[24];
  const float* v5  = (const float*)d_in[25];
  const float* L1  = (const float*)d_in[26];
  const float* gl1 = (const float*)d_in[27];
  const float* bl1 = (const float*)d_in[28];
  const float* ml1 = (const float*)d_in[29];
  const float* vl1 = (const float*)d_in[30];
  const float* L2  = (const float*)d_in[31];
  const float* L2b = (const float*)d_in[32];
  const float* gl2 = (const float*)d_in[33];
  const float* bl2 = (const float*)d_in[34];
  const float* ml2 = (const float*)d_in[35];
  const float* vl2 = (const float*)d_in[36];
  const float* L3  = (const float*)d_in[37];
  const float* L3b = (const float*)d_in[38];

  // workspace layout (float offsets). Dbuf (one batch, 64MB) aliases PQ:
  // per layer, D is dead after the scans, PQ written afterwards.
  float* ws   = (float*)d_ws;
  float* xt   = ws;                      //   262144
  float* sq   = ws + 262144;             //    32768
  int*   idx  = (int*)(ws + 294912);     //   655360 ints
  float* Dbuf = ws + 950272;             // 16777216 (= PQ region)
  float* PQ   = Dbuf;
  float* xc   = ws + 17727488;           // 16777216  (8,4096,512) concat x1..x4
  float* pmax = ws + 34504704;           //   262144
  float* psum = ws + 34766848;           //   262144
  float* pool = ws + 35028992;           //    16384
  float* oA   = ws + 35045376;           //     4096
  float* oB   = ws + 35049472;           //     2048
  if (ws_size < (size_t)35051520 * 4) return;  // ~140 MB scratch

  k_transpose_pad<<<128, 256, 0, stream>>>(x, xt);

  // ---- edge conv 1: in xt (C=6 padded to 8), out xc[:,:,0:64] ----
  k_sqnorm<<<128, 256, 0, stream>>>(xt, 8, 2, sq);
  for (int b = 0; b < NB; ++b){
    k_dgemm<8><<<dim3(32,32), 256, 0, stream>>>(xt + (size_t)b*NPTS*8, 8, 8, sq + b*NPTS, Dbuf);
    k_scan<<<1024, 256, 0, stream>>>(Dbuf, idx + (size_t)b*NPTS*KNN);
  }
  k_gemm_pq<<<dim3(256,2), 256, 0, stream>>>(xt, 8, 6, W1, 12, 64, PQ);
  k_gather_conv<<<8192, 256, 0, stream>>>(PQ, idx, g1, b1, m1, v1, xc, 6, 0);

  // ---- edge conv 2: in xc[:,:,0:64], out xc[:,:,64:128] ----
  k_sqnorm<<<128, 256, 0, stream>>>(xc, 512, 16, sq);
  for (int b = 0; b < NB; ++b){
    k_dgemm<32><<<dim3(32,32), 256, 0, stream>>>(xc + (size_t)b*NPTS*512, 512, 64, sq + b*NPTS, Dbuf);
    k_scan<<<1024, 256, 0, stream>>>(Dbuf, idx + (size_t)b*NPTS*KNN);
  }
  k_gemm_pq<<<dim3(256,2), 256, 0, stream>>>(xc, 512, 64, W2, 128, 64, PQ);
  k_gather_conv<<<8192, 256, 0, stream>>>(PQ, idx, g2, b2, m2, v2, xc, 6, 64);

  // ---- edge conv 3: in xc[:,:,64:128], out xc[:,:,128:256] ----
  k_sqnorm<<<128, 256, 0, stream>>>(xc + 64, 512, 16, sq);
  for (int b = 0; b < NB; ++b){
    k_dgemm<32><<<dim3(32,32), 256, 0, stream>>>(xc + 64 + (size_t)b*NPTS*512, 512, 64, sq + b*NPTS, Dbuf);
    k_scan<<<1024, 256, 0, stream>>>(Dbuf, idx + (size_t)b*NPTS*KNN);
  }
  k_gemm_pq<<<dim3(256,4), 256, 0, stream>>>(xc + 64, 512, 64, W3, 128, 128, PQ);
  k_gather_conv<<<16384, 256, 0, stream>>>(PQ, idx, g3, b3, m3, v3, xc, 7, 128);

  // ---- edge conv 4: in xc[:,:,128:256], out xc[:,:,256:512] ----
  k_sqnorm<<<128, 256, 0, stream>>>(xc + 128, 512, 32, sq);
  for (int b = 0; b < NB; ++b){
    k_dgemm<32><<<dim3(32,32), 256, 0, stream>>>(xc + 128 + (size_t)b*NPTS*512, 512, 128, sq + b*NPTS, Dbuf);
    k_scan<<<1024, 256, 0, stream>>>(Dbuf, idx + (size_t)b*NPTS*KNN);
  }
  k_gemm_pq<<<dim3(256,8), 256, 0, stream>>>(xc + 128, 512, 128, W4, 256, 256, PQ);
  k_gather_conv<<<32768, 256, 0, stream>>>(PQ, idx, g4, b4, m4, v4, xc, 8, 256);

  // ---- global feature: h = lrelu(bn(xc @ W5^T)), max+mean pool over N ----
  k_gemm_w5_pool<<<dim3(256,8), 256, 0, stream>>>(xc, W5, g5, b5, m5, v5, pmax, psum);
  k_pool_reduce<<<32, 256, 0, stream>>>(pmax, psum, pool);

  // ---- classifier head ----
  k_fc1<<<16, 256, 0, stream>>>(pool, L1, gl1, bl1, ml1, vl1, oA);
  k_fc2<<<8, 256, 0, stream>>>(oA, L2, L2b, gl2, bl2, ml2, vl2, oB);
  k_fc3<<<1, 64, 0, stream>>>(oB, L3, L3b, (float*)d_out);
}